// Round 6
// baseline (1857.848 us; speedup 1.0000x reference)
//
#include <hip/hip_runtime.h>
#include <cstddef>

// ---------------------------------------------------------------------------
// PolicyValueDWPixelPlayerAttnNoFFNNet — fp32, round 3 (resubmit: R4/R5 infra fail)
// Layout for all big activations: [b][n=h*32+w][m][c], c fastest (coalesced).
// R3: k_attn 512-thr blocks (16 waves/CU) + XOR-swizzled BUF staging.
// ---------------------------------------------------------------------------

#define WSX   0u
#define WST   8388608u
#define WSY   16777216u
#define WSS   25165824u
#define WSP   (WSS + 26624u)
#define WSPL  (WSP + 128u)

#define ATTN_LDS_BYTES ((4 * 64 * 64 + 8 * 64 * 8) * 4)  // 64KB W + 16KB BUF = 81920 B

__device__ __forceinline__ float silu_f(float x) { return x / (1.f + __expf(-x)); }

__device__ __forceinline__ float wsum64(float v) {
#pragma unroll
  for (int s = 1; s < 64; s <<= 1) v += __shfl_xor(v, s);
  return v;
}

// ---- init: zero stats, compute present mask --------------------------------
__global__ __launch_bounds__(256) void k_init(const float* __restrict__ board,
                                              float* __restrict__ ws) {
  int tid = threadIdx.x;
  for (unsigned i = blockIdx.x * 256 + tid; i < 26624u; i += 64u * 256u) ws[WSS + i] = 0.f;
  if (blockIdx.x == 0 && tid < 128) {
    int b = tid >> 3, m = tid & 7;
    float best = board[(size_t)(b * 149 + 7) * 1024];
    int bi = 0;
    for (int ch = 1; ch < 7; ++ch) {
      float v = board[(size_t)(b * 149 + 7 + ch) * 1024];
      if (v > best) { best = v; bi = ch; }
    }
    int m_each = bi + 2;  // 2..8
    ws[WSP + tid] = (m < m_each) ? 1.f : 0.f;
  }
}

// ---- stem: conv1x1 (35->64) into X + GN stats ------------------------------
__global__ __launch_bounds__(256) void k_stem(const float* __restrict__ board,
                                              const float* __restrict__ stem_w,
                                              float* __restrict__ ws) {
  __shared__ float A[147 * 64];   // [ch][pix]
  __shared__ float WT[35 * 64];   // [c][o]
  __shared__ float red_s[256], red_ss[256];
  int tid = threadIdx.x;
  int b = blockIdx.x >> 4, n0 = (blockIdx.x & 15) * 64;
  for (int i = tid; i < 147 * 64; i += 256) {
    int c = i >> 6, p = i & 63;
    A[i] = board[(size_t)(b * 149 + c) * 1024 + n0 + p];
  }
  for (int i = tid; i < 35 * 64; i += 256) {
    int o = i / 35, c = i % 35;           // coalesced read of stem_w[o][c]
    WT[c * 64 + o] = stem_w[i];
  }
  __syncthreads();
  int o = tid & 63, wv = tid >> 6;
  float* X = ws + WSX;
  float st_s[8], st_ss[8];
#pragma unroll
  for (int m = 0; m < 8; ++m) { st_s[m] = 0.f; st_ss[m] = 0.f; }
  for (int m = 0; m < 8; ++m) {
    for (int k = 0; k < 4; ++k) {
      int q = wv + 4 * k;  // pixel quad 0..15
      float a0 = 0.f, a1 = 0.f, a2 = 0.f, a3 = 0.f;
#pragma unroll
      for (int c = 0; c < 19; ++c) {
        float w = WT[c * 64 + o];
        float4 av = *(const float4*)&A[c * 64 + q * 4];
        a0 += av.x * w; a1 += av.y * w; a2 += av.z * w; a3 += av.w * w;
      }
#pragma unroll
      for (int j = 0; j < 16; ++j) {
        float w = WT[(19 + j) * 64 + o];
        float4 av = *(const float4*)&A[(19 + m * 16 + j) * 64 + q * 4];
        a0 += av.x * w; a1 += av.y * w; a2 += av.z * w; a3 += av.w * w;
      }
      int n = n0 + q * 4;
      float vals[4] = {a0, a1, a2, a3};
#pragma unroll
      for (int j = 0; j < 4; ++j) {
        X[((size_t)(b * 1024 + n + j) * 8 + m) * 64 + o] = vals[j];
        st_s[m] += vals[j];
        st_ss[m] += vals[j] * vals[j];
      }
    }
  }
  float* stats = ws + WSS;  // stage 0 (stem)
  for (int m = 0; m < 8; ++m) {
    __syncthreads();
    red_s[tid] = st_s[m];
    red_ss[tid] = st_ss[m];
    __syncthreads();
    if (tid < 8) {
      float a = 0.f, a2 = 0.f;
      for (int w4 = 0; w4 < 4; ++w4)
        for (int j = 0; j < 8; ++j) {
          int t2 = w4 * 64 + tid * 8 + j;
          a += red_s[t2]; a2 += red_ss[t2];
        }
      atomicAdd(&stats[((b * 8 + m) * 8 + tid) * 2 + 0], a);
      atomicAdd(&stats[((b * 8 + m) * 8 + tid) * 2 + 1], a2);
    }
  }
}

// ---- apply GN (+weights) + SiLU in place on X (used for stem) --------------
__global__ __launch_bounds__(256) void k_gn_silu(float* __restrict__ X,
                                                 const float* __restrict__ g,
                                                 const float* __restrict__ bt,
                                                 const float* __restrict__ stats) {
  for (size_t idx = (size_t)blockIdx.x * 256 + threadIdx.x; idx < 8388608ull;
       idx += (size_t)2048 * 256) {
    int c = (int)(idx & 63);
    int m = (int)((idx >> 6) & 7);
    int b = (int)(idx >> 19);
    int gi = ((b * 8 + m) * 8 + (c >> 3)) * 2;
    float s = stats[gi], s2 = stats[gi + 1];
    float mean = s * (1.f / 8192.f);
    float var = s2 * (1.f / 8192.f) - mean * mean;
    float rstd = rsqrtf(var + 1e-5f);
    float v = (X[idx] - mean) * rstd * g[c] + bt[c];
    X[idx] = silu_f(v);
  }
}

// ---- fused per-pixel attention + residual + LayerNorm ----------------------
#define FMA8(acc, WW)                                                      \
  acc[0] += t0.x * (WW); acc[1] += t0.y * (WW); acc[2] += t0.z * (WW);     \
  acc[3] += t0.w * (WW); acc[4] += t1.x * (WW); acc[5] += t1.y * (WW);     \
  acc[6] += t1.z * (WW); acc[7] += t1.w * (WW);

__global__ __launch_bounds__(512) void k_attn(
    const float* __restrict__ X, float* __restrict__ T,
    const float* __restrict__ qw, const float* __restrict__ qb,
    const float* __restrict__ kw, const float* __restrict__ kb,
    const float* __restrict__ vw, const float* __restrict__ vb,
    const float* __restrict__ ow, const float* __restrict__ ob,
    const float* __restrict__ lng, const float* __restrict__ lnb,
    const float* __restrict__ present) {
  extern __shared__ float sm[];
  float* Wq = sm;              // [c][o]
  float* Wk = sm + 4096;
  float* Wv = sm + 8192;
  float* Wo = sm + 12288;
  float* BUF = sm + 16384;     // [wave][64][8], XOR-swizzled
  int tid = threadIdx.x;
  int lane = tid & 63, wv = tid >> 6;              // wv 0..7
  int b = blockIdx.x >> 5;                         // 512 blocks: 16 b x 32 groups
  int n0 = (blockIdx.x & 31) * 32;
  for (int i = tid; i < 4096; i += 512) {
    int o = i >> 6, c = i & 63;
    Wq[c * 64 + o] = qw[i];
    Wk[c * 64 + o] = kw[i];
    Wv[c * 64 + o] = vw[i];
    Wo[c * 64 + o] = ow[i];
  }
  float bq = qb[lane], bk = kb[lane], bv = vb[lane], bo = ob[lane];
  float gl = lng[lane], bl = lnb[lane];
  unsigned pmask = 0;
#pragma unroll
  for (int m = 0; m < 8; ++m) pmask |= (present[b * 8 + m] > 0.5f) ? (1u << m) : 0u;
  __syncthreads();
  float* bw = BUF + wv * 512;
  const int sw = lane & 12;   // XOR swizzle: spreads b128 start banks 4 -> 8
  for (int j = 0; j < 4; ++j) {
    int n = n0 + wv * 4 + j;
    const float* xp = X + ((size_t)(b * 1024 + n) * 8) * 64 + lane;
    float tok[8];
#pragma unroll
    for (int m = 0; m < 8; ++m) tok[m] = xp[m * 64];
    *(float4*)&bw[(lane * 8) ^ sw]     = make_float4(tok[0], tok[1], tok[2], tok[3]);
    *(float4*)&bw[(lane * 8 + 4) ^ sw] = make_float4(tok[4], tok[5], tok[6], tok[7]);
    __asm__ volatile("" ::: "memory");
    float aq[8], ak[8], av[8];
#pragma unroll
    for (int m = 0; m < 8; ++m) { aq[m] = bq; ak[m] = bk; av[m] = bv; }
#pragma unroll
    for (int c = 0; c < 64; ++c) {
      float4 t0 = *(const float4*)&bw[(c * 8) ^ (c & 12)];
      float4 t1 = *(const float4*)&bw[(c * 8 + 4) ^ (c & 12)];
      float wq_ = Wq[c * 64 + lane];
      float wk_ = Wk[c * 64 + lane];
      float wv_ = Wv[c * 64 + lane];
      FMA8(aq, wq_)
      FMA8(ak, wk_)
      FMA8(av, wv_)
    }
    // attention: lane holds channel o; head = o>>4; reduce over 16-lane group
    float ao[8];
#pragma unroll
    for (int mq = 0; mq < 8; ++mq) {
      float lg[8];
#pragma unroll
      for (int mk = 0; mk < 8; ++mk) {
        float pp = aq[mq] * ak[mk];
        pp += __shfl_xor(pp, 1);
        pp += __shfl_xor(pp, 2);
        pp += __shfl_xor(pp, 4);
        pp += __shfl_xor(pp, 8);
        lg[mk] = pp * 0.25f;  // hd^-0.5 = 1/4
      }
      float mx = -3.0e38f;
#pragma unroll
      for (int mk = 0; mk < 8; ++mk)
        if ((pmask >> mk) & 1) mx = fmaxf(mx, lg[mk]);
      float se = 0.f, acc = 0.f;
#pragma unroll
      for (int mk = 0; mk < 8; ++mk) {
        float e = ((pmask >> mk) & 1) ? __expf(lg[mk] - mx) : 0.f;
        se += e;
        acc += e * av[mk];
      }
      ao[mq] = acc / se;
    }
    __asm__ volatile("" ::: "memory");
    *(float4*)&bw[(lane * 8) ^ sw]     = make_float4(ao[0], ao[1], ao[2], ao[3]);
    *(float4*)&bw[(lane * 8 + 4) ^ sw] = make_float4(ao[4], ao[5], ao[6], ao[7]);
    __asm__ volatile("" ::: "memory");
    float z[8];
#pragma unroll
    for (int m = 0; m < 8; ++m) z[m] = bo;
#pragma unroll
    for (int c = 0; c < 64; ++c) {
      float4 t0 = *(const float4*)&bw[(c * 8) ^ (c & 12)];
      float4 t1 = *(const float4*)&bw[(c * 8 + 4) ^ (c & 12)];
      float wo_ = Wo[c * 64 + lane];
      FMA8(z, wo_)
    }
    float* tp = T + ((size_t)(b * 1024 + n) * 8) * 64 + lane;
#pragma unroll
    for (int m = 0; m < 8; ++m) {
      float r = tok[m] + z[m];
      float mean = wsum64(r) * (1.f / 64.f);
      float d = r - mean;
      float var = wsum64(d * d) * (1.f / 64.f);
      float rstd = rsqrtf(var + 1e-5f);
      tp[m * 64] = d * rstd * gl + bl;
    }
    __asm__ volatile("" ::: "memory");
  }
}

// ---- depthwise 3x3 (SAME, zero pad) + GN1 stats ----------------------------
__global__ __launch_bounds__(256) void k_dw(const float* __restrict__ T, float* __restrict__ Y,
                                            const float* __restrict__ dww,
                                            float* __restrict__ stats) {
  __shared__ float red_s[256], red_ss[256];
  int tid = threadIdx.x, lane = tid & 63, wv = tid >> 6;
  int bm = blockIdx.x >> 3, rg = blockIdx.x & 7;
  int b = bm >> 3, m = bm & 7;
  int r = rg * 4 + wv;  // row 0..31
  float w9[9];
#pragma unroll
  for (int k = 0; k < 9; ++k) w9[k] = dww[lane * 9 + k];
  float s = 0.f, ss = 0.f;
  const size_t base = (size_t)b * 1024 * 512 + (size_t)m * 64 + lane;  // + n*512
  for (int col = 0; col < 32; ++col) {
    float acc = 0.f;
#pragma unroll
    for (int dh = -1; dh <= 1; ++dh) {
      int rr = r + dh;
      if (rr < 0 || rr > 31) continue;
#pragma unroll
      for (int dx = -1; dx <= 1; ++dx) {
        int cc = col + dx;
        if (cc < 0 || cc > 31) continue;
        acc += T[base + (size_t)(rr * 32 + cc) * 512] * w9[(dh + 1) * 3 + dx + 1];
      }
    }
    Y[base + (size_t)(r * 32 + col) * 512] = acc;
    s += acc;
    ss += acc * acc;
  }
  red_s[tid] = s;
  red_ss[tid] = ss;
  __syncthreads();
  if (tid < 8) {
    float a = 0.f, a2 = 0.f;
    for (int w4 = 0; w4 < 4; ++w4)
      for (int j = 0; j < 8; ++j) {
        int t2 = w4 * 64 + tid * 8 + j;
        a += red_s[t2]; a2 += red_ss[t2];
      }
    atomicAdd(&stats[(bm * 8 + tid) * 2 + 0], a);
    atomicAdd(&stats[(bm * 8 + tid) * 2 + 1], a2);
  }
}

// ---- GN1-apply + SiLU + pw conv1x1 (in place on Y) + GN2 stats -------------
__global__ __launch_bounds__(256) void k_pw(float* __restrict__ Y, const float* __restrict__ pw,
                                            const float* __restrict__ g1,
                                            const float* __restrict__ b1,
                                            const float* __restrict__ s1,
                                            float* __restrict__ s2) {
  __shared__ float PWT[4096];     // [c][o]
  __shared__ float HB[4][256];    // per wave: [lane][4 pixels]
  __shared__ float red_s[256], red_ss[256];
  int tid = threadIdx.x, lane = tid & 63, wv = tid >> 6;
  int bm = blockIdx.x >> 2, pt = blockIdx.x & 3;
  int b = bm >> 3, m = bm & 7;
  int n0 = pt * 256;
  for (int i = tid; i < 4096; i += 256) {
    int o = i >> 6, c = i & 63;
    PWT[c * 64 + o] = pw[i];
  }
  int g = lane >> 3;
  float sg = s1[(bm * 8 + g) * 2], sg2 = s1[(bm * 8 + g) * 2 + 1];
  float mean = sg * (1.f / 8192.f);
  float var = sg2 * (1.f / 8192.f) - mean * mean;
  float rstd = rsqrtf(var + 1e-5f);
  float A = rstd * g1[lane];
  float Bc = b1[lane] - mean * A;
  __syncthreads();
  float st = 0.f, st2 = 0.f;
  const size_t base = (size_t)b * 1024 * 512 + (size_t)m * 64 + lane;
  for (int it = 0; it < 16; ++it) {
    int n = n0 + it * 16 + wv * 4;
    float h[4];
#pragma unroll
    for (int jj = 0; jj < 4; ++jj) {
      float y = Y[base + (size_t)(n + jj) * 512];
      h[jj] = silu_f(y * A + Bc);
    }
    *(float4*)&HB[wv][lane * 4] = make_float4(h[0], h[1], h[2], h[3]);
    __asm__ volatile("" ::: "memory");
    float a0 = 0.f, a1 = 0.f, a2 = 0.f, a3 = 0.f;
#pragma unroll 8
    for (int c = 0; c < 64; ++c) {
      float4 hh = *(const float4*)&HB[wv][c * 4];
      float w = PWT[c * 64 + lane];
      a0 += hh.x * w; a1 += hh.y * w; a2 += hh.z * w; a3 += hh.w * w;
    }
    float vals[4] = {a0, a1, a2, a3};
#pragma unroll
    for (int jj = 0; jj < 4; ++jj) {
      Y[base + (size_t)(n + jj) * 512] = vals[jj];
      st += vals[jj];
      st2 += vals[jj] * vals[jj];
    }
    __asm__ volatile("" ::: "memory");
  }
  red_s[tid] = st;
  red_ss[tid] = st2;
  __syncthreads();
  if (tid < 8) {
    float a = 0.f, a2 = 0.f;
    for (int w4 = 0; w4 < 4; ++w4)
      for (int j = 0; j < 8; ++j) {
        int t2 = w4 * 64 + tid * 8 + j;
        a += red_s[t2]; a2 += red_ss[t2];
      }
    atomicAdd(&s2[(bm * 8 + tid) * 2 + 0], a);
    atomicAdd(&s2[(bm * 8 + tid) * 2 + 1], a2);
  }
}

// ---- GN2-apply + residual + SiLU + present mask -> X -----------------------
__global__ __launch_bounds__(256) void k_fuse(const float* __restrict__ T,
                                              const float* __restrict__ Y,
                                              float* __restrict__ X,
                                              const float* __restrict__ g2,
                                              const float* __restrict__ b2,
                                              const float* __restrict__ s2,
                                              const float* __restrict__ present) {
  int tid = threadIdx.x, lane = tid & 63, wv = tid >> 6;
  int bm = blockIdx.x >> 3, pt = blockIdx.x & 7;
  int b = bm >> 3, m = bm & 7;
  int g = lane >> 3;
  float sg = s2[(bm * 8 + g) * 2], sg2 = s2[(bm * 8 + g) * 2 + 1];
  float mean = sg * (1.f / 8192.f);
  float var = sg2 * (1.f / 8192.f) - mean * mean;
  float rstd = rsqrtf(var + 1e-5f);
  float A = rstd * g2[lane];
  float Bc = b2[lane] - mean * A;
  float pres = present[bm];
  const size_t base = (size_t)b * 1024 * 512 + (size_t)m * 64 + lane;
  int n0 = pt * 128;
  for (int i2 = 0; i2 < 32; ++i2) {
    int n = n0 + i2 * 4 + wv;
    size_t idx = base + (size_t)n * 512;
    float z = T[idx] + (Y[idx] * A + Bc);
    X[idx] = silu_f(z) * pres;
  }
}

// ---- heads: policy logits + opp_move ---------------------------------------
__global__ __launch_bounds__(256) void k_heads_px(const float* __restrict__ X,
                                                  const float* __restrict__ pol_w,
                                                  const float* __restrict__ pol_b,
                                                  const float* __restrict__ om_w,
                                                  const float* __restrict__ om_b,
                                                  const float* __restrict__ present,
                                                  float* __restrict__ out) {
  int tid = threadIdx.x, lane = tid & 63, wv = tid >> 6;
  int b = blockIdx.x >> 4, n0 = (blockIdx.x & 15) * 64;
  float pw_ = pol_w[lane];
  for (int it = 0; it < 16; ++it) {
    int n = n0 + wv * 16 + it;
    const float* xp = X + ((size_t)(b * 1024 + n) * 8) * 64 + lane;
#pragma unroll
    for (int m = 0; m < 8; ++m) {
      float v = xp[m * 64];
      float d = wsum64(v * om_w[m * 64 + lane]);
      if (m == 0) {
        float dp = wsum64(v * pw_);
        if (lane == 0) out[b * 1024 + n] = dp + pol_b[0];
      }
      if (lane == 0)
        out[16400u + (size_t)(b * 8 + m) * 1024 + n] = (d + om_b[m]) * present[b * 8 + m];
    }
  }
}

// ---- heads: spatial mean pool ----------------------------------------------
__global__ __launch_bounds__(256) void k_pool(const float* __restrict__ X,
                                              float* __restrict__ pooled) {
  __shared__ float red[256];
  int tid = threadIdx.x, lane = tid & 63, wv = tid >> 6;
  int b = blockIdx.x >> 3, m = blockIdx.x & 7;
  float s = 0.f;
  for (int p = wv; p < 1024; p += 4)
    s += X[((size_t)(b * 1024 + p) * 8 + m) * 64 + lane];
  red[tid] = s;
  __syncthreads();
  if (tid < 64)
    pooled[(b * 8 + m) * 64 + tid] =
        (red[tid] + red[tid + 64] + red[tid + 128] + red[tid + 192]) * (1.f / 1024.f);
}

// ---- heads: value MLP + opp_param MLP --------------------------------------
__global__ __launch_bounds__(64) void k_heads_vec(
    const float* __restrict__ pooled, const float* __restrict__ vh_w1,
    const float* __restrict__ vh_b1, const float* __restrict__ vh_w2,
    const float* __restrict__ vh_b2, const float* __restrict__ op_w1,
    const float* __restrict__ op_b1, const float* __restrict__ op_w2,
    const float* __restrict__ op_b2, const float* __restrict__ present,
    float* __restrict__ out) {
  int lane = threadIdx.x;
  int b = blockIdx.x >> 3, m = blockIdx.x & 7;
  const float* pp = pooled + (b * 8 + m) * 64;
  float h = op_b1[lane];
  for (int c = 0; c < 64; ++c) h += pp[c] * op_w1[lane * 64 + c];
  h = silu_f(h);
  float pres = present[b * 8 + m];
  for (int jj = 0; jj < 5; ++jj) {
    float d = wsum64(h * op_w2[(m * 5 + jj) * 64 + lane]);
    if (lane == 0) out[147472u + (b * 8 + m) * 5 + jj] = (d + op_b2[m * 5 + jj]) * pres;
  }
  if (m == 0) {
    float hv = vh_b1[lane];
    for (int c = 0; c < 64; ++c) hv += pp[c] * vh_w1[lane * 64 + c];
    hv = silu_f(hv);
    float dv = wsum64(hv * vh_w2[lane]);
    if (lane == 0) out[16384u + b] = dv + vh_b2[0];
  }
}

// ---------------------------------------------------------------------------
extern "C" void kernel_launch(void* const* d_in, const int* in_sizes, int n_in,
                              void* d_out, int out_size, void* d_ws, size_t ws_size,
                              hipStream_t stream) {
  const float* board  = (const float*)d_in[0];
  const float* stem_w = (const float*)d_in[1];
  const float* stem_g = (const float*)d_in[2];
  const float* stem_b = (const float*)d_in[3];
  const float* qw = (const float*)d_in[4];
  const float* qb = (const float*)d_in[5];
  const float* kw = (const float*)d_in[6];
  const float* kb = (const float*)d_in[7];
  const float* vw = (const float*)d_in[8];
  const float* vb = (const float*)d_in[9];
  const float* ow = (const float*)d_in[10];
  const float* ob = (const float*)d_in[11];
  const float* ln_g = (const float*)d_in[12];
  const float* ln_b = (const float*)d_in[13];
  const float* dw_w = (const float*)d_in[14];
  const float* gn1_g = (const float*)d_in[15];
  const float* gn1_b = (const float*)d_in[16];
  const float* pw_w = (const float*)d_in[17];
  const float* gn2_g = (const float*)d_in[18];
  const float* gn2_b = (const float*)d_in[19];
  const float* pol_w = (const float*)d_in[20];
  const float* pol_b = (const float*)d_in[21];
  const float* vh_w1 = (const float*)d_in[22];
  const float* vh_b1 = (const float*)d_in[23];
  const float* vh_w2 = (const float*)d_in[24];
  const float* vh_b2 = (const float*)d_in[25];
  const float* om_w = (const float*)d_in[26];
  const float* om_b = (const float*)d_in[27];
  const float* op_w1 = (const float*)d_in[28];
  const float* op_b1 = (const float*)d_in[29];
  const float* op_w2 = (const float*)d_in[30];
  const float* op_b2 = (const float*)d_in[31];
  float* ws = (float*)d_ws;
  float* out = (float*)d_out;

  (void)hipFuncSetAttribute((const void*)k_attn,
                            hipFuncAttributeMaxDynamicSharedMemorySize,
                            ATTN_LDS_BYTES);

  k_init<<<64, 256, 0, stream>>>(board, ws);
  k_stem<<<256, 256, 0, stream>>>(board, stem_w, ws);
  k_gn_silu<<<2048, 256, 0, stream>>>(ws + WSX, stem_g, stem_b, ws + WSS);

  for (int i = 0; i < 6; ++i) {
    float* s1 = ws + WSS + (size_t)(1 + 2 * i) * 2048;
    float* s2 = ws + WSS + (size_t)(2 + 2 * i) * 2048;
    k_attn<<<512, 512, ATTN_LDS_BYTES, stream>>>(
        ws + WSX, ws + WST, qw + i * 4096, qb + i * 64, kw + i * 4096, kb + i * 64,
        vw + i * 4096, vb + i * 64, ow + i * 4096, ob + i * 64, ln_g + i * 64,
        ln_b + i * 64, ws + WSP);
    k_dw<<<1024, 256, 0, stream>>>(ws + WST, ws + WSY, dw_w + i * 576, s1);
    k_pw<<<512, 256, 0, stream>>>(ws + WSY, pw_w + i * 4096, gn1_g + i * 64,
                                  gn1_b + i * 64, s1, s2);
    k_fuse<<<1024, 256, 0, stream>>>(ws + WST, ws + WSY, ws + WSX, gn2_g + i * 64,
                                     gn2_b + i * 64, s2, ws + WSP);
  }

  k_heads_px<<<256, 256, 0, stream>>>(ws + WSX, pol_w, pol_b, om_w, om_b, ws + WSP, out);
  k_pool<<<128, 256, 0, stream>>>(ws + WSX, ws + WSPL);
  k_heads_vec<<<128, 64, 0, stream>>>(ws + WSPL, vh_w1, vh_b1, vh_w2, vh_b2, op_w1,
                                      op_b1, op_w2, op_b2, ws + WSP, out);
}

// Round 8
// 1682.143 us; speedup vs baseline: 1.1045x; 1.1045x over previous
//
#include <hip/hip_runtime.h>
#include <cstddef>

// ---------------------------------------------------------------------------
// PolicyValueDWPixelPlayerAttnNoFFNNet — fp32, round 6 (resubmit: R7 infra fail)
// Layout for all big activations: [b][n=h*32+w][m][c], c fastest (coalesced).
// R6: k_attn rewritten — token broadcast via v_readlane (VALU) instead of LDS
//     BUF; head-group reductions via DPP row_ror adds (VALU) instead of
//     ds_swizzle. LDS = weights only (64KB) -> 2 blocks/CU, 16 waves/CU.
// ---------------------------------------------------------------------------

#define WSX   0u
#define WST   8388608u
#define WSY   16777216u
#define WSS   25165824u
#define WSP   (WSS + 26624u)
#define WSPL  (WSP + 128u)

#define ATTN_LDS_BYTES (4 * 64 * 64 * 4)  // 4 weight mats, 64KB

__device__ __forceinline__ float silu_f(float x) { return x / (1.f + __expf(-x)); }

__device__ __forceinline__ float wsum64(float v) {
#pragma unroll
  for (int s = 1; s < 64; s <<= 1) v += __shfl_xor(v, s);
  return v;
}

// broadcast lane l's value to all lanes (VALU, no LDS)
__device__ __forceinline__ float bcastlane(float v, int l) {
  return __int_as_float(__builtin_amdgcn_readlane(__float_as_int(v), l));
}

// sum within each 16-lane DPP row (VALU, no LDS): ror 8,4,2,1
__device__ __forceinline__ float rowsum16(float v) {
  v += __int_as_float(__builtin_amdgcn_update_dpp(0, __float_as_int(v), 0x128, 0xf, 0xf, true));
  v += __int_as_float(__builtin_amdgcn_update_dpp(0, __float_as_int(v), 0x124, 0xf, 0xf, true));
  v += __int_as_float(__builtin_amdgcn_update_dpp(0, __float_as_int(v), 0x122, 0xf, 0xf, true));
  v += __int_as_float(__builtin_amdgcn_update_dpp(0, __float_as_int(v), 0x121, 0xf, 0xf, true));
  return v;
}

// full 64-lane sum: DPP within rows, ds_swizzle across rows (only 2 LDS ops)
__device__ __forceinline__ float wsum64b(float v) {
  v = rowsum16(v);
  v += __shfl_xor(v, 16);
  v += __shfl_xor(v, 32);
  return v;
}

// ---- init: zero stats, compute present mask --------------------------------
__global__ __launch_bounds__(256) void k_init(const float* __restrict__ board,
                                              float* __restrict__ ws) {
  int tid = threadIdx.x;
  for (unsigned i = blockIdx.x * 256 + tid; i < 26624u; i += 64u * 256u) ws[WSS + i] = 0.f;
  if (blockIdx.x == 0 && tid < 128) {
    int b = tid >> 3, m = tid & 7;
    float best = board[(size_t)(b * 149 + 7) * 1024];
    int bi = 0;
    for (int ch = 1; ch < 7; ++ch) {
      float v = board[(size_t)(b * 149 + 7 + ch) * 1024];
      if (v > best) { best = v; bi = ch; }
    }
    int m_each = bi + 2;  // 2..8
    ws[WSP + tid] = (m < m_each) ? 1.f : 0.f;
  }
}

// ---- stem: conv1x1 (35->64) into X + GN stats ------------------------------
__global__ __launch_bounds__(256) void k_stem(const float* __restrict__ board,
                                              const float* __restrict__ stem_w,
                                              float* __restrict__ ws) {
  __shared__ float A[147 * 64];   // [ch][pix]
  __shared__ float WT[35 * 64];   // [c][o]
  __shared__ float red_s[256], red_ss[256];
  int tid = threadIdx.x;
  int b = blockIdx.x >> 4, n0 = (blockIdx.x & 15) * 64;
  for (int i = tid; i < 147 * 64; i += 256) {
    int c = i >> 6, p = i & 63;
    A[i] = board[(size_t)(b * 149 + c) * 1024 + n0 + p];
  }
  for (int i = tid; i < 35 * 64; i += 256) {
    int o = i / 35, c = i % 35;           // coalesced read of stem_w[o][c]
    WT[c * 64 + o] = stem_w[i];
  }
  __syncthreads();
  int o = tid & 63, wv = tid >> 6;
  float* X = ws + WSX;
  float st_s[8], st_ss[8];
#pragma unroll
  for (int m = 0; m < 8; ++m) { st_s[m] = 0.f; st_ss[m] = 0.f; }
  for (int m = 0; m < 8; ++m) {
    for (int k = 0; k < 4; ++k) {
      int q = wv + 4 * k;  // pixel quad 0..15
      float a0 = 0.f, a1 = 0.f, a2 = 0.f, a3 = 0.f;
#pragma unroll
      for (int c = 0; c < 19; ++c) {
        float w = WT[c * 64 + o];
        float4 av = *(const float4*)&A[c * 64 + q * 4];
        a0 += av.x * w; a1 += av.y * w; a2 += av.z * w; a3 += av.w * w;
      }
#pragma unroll
      for (int j = 0; j < 16; ++j) {
        float w = WT[(19 + j) * 64 + o];
        float4 av = *(const float4*)&A[(19 + m * 16 + j) * 64 + q * 4];
        a0 += av.x * w; a1 += av.y * w; a2 += av.z * w; a3 += av.w * w;
      }
      int n = n0 + q * 4;
      float vals[4] = {a0, a1, a2, a3};
#pragma unroll
      for (int j = 0; j < 4; ++j) {
        X[((size_t)(b * 1024 + n + j) * 8 + m) * 64 + o] = vals[j];
        st_s[m] += vals[j];
        st_ss[m] += vals[j] * vals[j];
      }
    }
  }
  float* stats = ws + WSS;  // stage 0 (stem)
  for (int m = 0; m < 8; ++m) {
    __syncthreads();
    red_s[tid] = st_s[m];
    red_ss[tid] = st_ss[m];
    __syncthreads();
    if (tid < 8) {
      float a = 0.f, a2 = 0.f;
      for (int w4 = 0; w4 < 4; ++w4)
        for (int j = 0; j < 8; ++j) {
          int t2 = w4 * 64 + tid * 8 + j;
          a += red_s[t2]; a2 += red_ss[t2];
        }
      atomicAdd(&stats[((b * 8 + m) * 8 + tid) * 2 + 0], a);
      atomicAdd(&stats[((b * 8 + m) * 8 + tid) * 2 + 1], a2);
    }
  }
}

// ---- apply GN (+weights) + SiLU in place on X (used for stem) --------------
__global__ __launch_bounds__(256) void k_gn_silu(float* __restrict__ X,
                                                 const float* __restrict__ g,
                                                 const float* __restrict__ bt,
                                                 const float* __restrict__ stats) {
  for (size_t idx = (size_t)blockIdx.x * 256 + threadIdx.x; idx < 8388608ull;
       idx += (size_t)2048 * 256) {
    int c = (int)(idx & 63);
    int m = (int)((idx >> 6) & 7);
    int b = (int)(idx >> 19);
    int gi = ((b * 8 + m) * 8 + (c >> 3)) * 2;
    float s = stats[gi], s2 = stats[gi + 1];
    float mean = s * (1.f / 8192.f);
    float var = s2 * (1.f / 8192.f) - mean * mean;
    float rstd = rsqrtf(var + 1e-5f);
    float v = (X[idx] - mean) * rstd * g[c] + bt[c];
    X[idx] = silu_f(v);
  }
}

// ---- fused per-pixel attention + residual + LayerNorm ----------------------
__global__ __launch_bounds__(512, 4) void k_attn(
    const float* __restrict__ X, float* __restrict__ T,
    const float* __restrict__ qw, const float* __restrict__ qb,
    const float* __restrict__ kw, const float* __restrict__ kb,
    const float* __restrict__ vw, const float* __restrict__ vb,
    const float* __restrict__ ow, const float* __restrict__ ob,
    const float* __restrict__ lng, const float* __restrict__ lnb,
    const float* __restrict__ present) {
  extern __shared__ float sm[];
  float* Wq = sm;              // [c][o]
  float* Wk = sm + 4096;
  float* Wv = sm + 8192;
  float* Wo = sm + 12288;
  int tid = threadIdx.x;
  int lane = tid & 63, wv = tid >> 6;              // wv 0..7
  int b = blockIdx.x >> 5;                         // 512 blocks: 16 b x 32 groups
  int n0 = (blockIdx.x & 31) * 32;
  for (int i = tid; i < 4096; i += 512) {
    int o = i >> 6, c = i & 63;
    Wq[c * 64 + o] = qw[i];
    Wk[c * 64 + o] = kw[i];
    Wv[c * 64 + o] = vw[i];
    Wo[c * 64 + o] = ow[i];
  }
  float bq = qb[lane], bk = kb[lane], bv = vb[lane], bo = ob[lane];
  float gl = lng[lane], bl = lnb[lane];
  unsigned pmask = 0;
#pragma unroll
  for (int m = 0; m < 8; ++m) pmask |= (present[b * 8 + m] > 0.5f) ? (1u << m) : 0u;
  __syncthreads();
  for (int j = 0; j < 4; ++j) {
    int n = n0 + wv * 4 + j;
    const float* xp = X + ((size_t)(b * 1024 + n) * 8) * 64 + lane;
    float tok[8];
#pragma unroll
    for (int m = 0; m < 8; ++m) tok[m] = xp[m * 64];
    // qkv projections: token broadcast via readlane (VALU), weights from LDS
    float aq[8], ak[8], av[8];
#pragma unroll
    for (int m = 0; m < 8; ++m) { aq[m] = bq; ak[m] = bk; av[m] = bv; }
#pragma unroll 16
    for (int c = 0; c < 64; ++c) {
      float wq_ = Wq[c * 64 + lane];
      float wk_ = Wk[c * 64 + lane];
      float wv_ = Wv[c * 64 + lane];
#pragma unroll
      for (int m = 0; m < 8; ++m) {
        float t = bcastlane(tok[m], c);
        aq[m] = fmaf(t, wq_, aq[m]);
        ak[m] = fmaf(t, wk_, ak[m]);
        av[m] = fmaf(t, wv_, av[m]);
      }
    }
    // attention: lane holds channel o; head = o>>4; reduce via DPP row sums
    float ao[8];
#pragma unroll
    for (int mq = 0; mq < 8; ++mq) {
      float lg[8];
#pragma unroll
      for (int mk = 0; mk < 8; ++mk)
        lg[mk] = rowsum16(aq[mq] * ak[mk]) * 0.25f;  // hd^-0.5 = 1/4
      float mx = -3.0e38f;
#pragma unroll
      for (int mk = 0; mk < 8; ++mk)
        if ((pmask >> mk) & 1) mx = fmaxf(mx, lg[mk]);
      float se = 0.f, acc = 0.f;
#pragma unroll
      for (int mk = 0; mk < 8; ++mk) {
        float e = ((pmask >> mk) & 1) ? __expf(lg[mk] - mx) : 0.f;
        se += e;
        acc += e * av[mk];
      }
      ao[mq] = acc / se;
    }
    // o-projection: ao broadcast via readlane
    float z[8];
#pragma unroll
    for (int m = 0; m < 8; ++m) z[m] = bo;
#pragma unroll 16
    for (int c = 0; c < 64; ++c) {
      float wo_ = Wo[c * 64 + lane];
#pragma unroll
      for (int m = 0; m < 8; ++m)
        z[m] = fmaf(bcastlane(ao[m], c), wo_, z[m]);
    }
    // residual + LayerNorm
    float* tp = T + ((size_t)(b * 1024 + n) * 8) * 64 + lane;
#pragma unroll
    for (int m = 0; m < 8; ++m) {
      float r = tok[m] + z[m];
      float mean = wsum64b(r) * (1.f / 64.f);
      float d = r - mean;
      float var = wsum64b(d * d) * (1.f / 64.f);
      float rstd = rsqrtf(var + 1e-5f);
      tp[m * 64] = d * rstd * gl + bl;
    }
  }
}

// ---- depthwise 3x3 (SAME, zero pad) + GN1 stats ----------------------------
__global__ __launch_bounds__(256) void k_dw(const float* __restrict__ T, float* __restrict__ Y,
                                            const float* __restrict__ dww,
                                            float* __restrict__ stats) {
  __shared__ float red_s[256], red_ss[256];
  int tid = threadIdx.x, lane = tid & 63, wv = tid >> 6;
  int bm = blockIdx.x >> 3, rg = blockIdx.x & 7;
  int b = bm >> 3, m = bm & 7;
  int r = rg * 4 + wv;  // row 0..31
  float w9[9];
#pragma unroll
  for (int k = 0; k < 9; ++k) w9[k] = dww[lane * 9 + k];
  float s = 0.f, ss = 0.f;
  const size_t base = (size_t)b * 1024 * 512 + (size_t)m * 64 + lane;  // + n*512
  for (int col = 0; col < 32; ++col) {
    float acc = 0.f;
#pragma unroll
    for (int dh = -1; dh <= 1; ++dh) {
      int rr = r + dh;
      if (rr < 0 || rr > 31) continue;
#pragma unroll
      for (int dx = -1; dx <= 1; ++dx) {
        int cc = col + dx;
        if (cc < 0 || cc > 31) continue;
        acc += T[base + (size_t)(rr * 32 + cc) * 512] * w9[(dh + 1) * 3 + dx + 1];
      }
    }
    Y[base + (size_t)(r * 32 + col) * 512] = acc;
    s += acc;
    ss += acc * acc;
  }
  red_s[tid] = s;
  red_ss[tid] = ss;
  __syncthreads();
  if (tid < 8) {
    float a = 0.f, a2 = 0.f;
    for (int w4 = 0; w4 < 4; ++w4)
      for (int j = 0; j < 8; ++j) {
        int t2 = w4 * 64 + tid * 8 + j;
        a += red_s[t2]; a2 += red_ss[t2];
      }
    atomicAdd(&stats[(bm * 8 + tid) * 2 + 0], a);
    atomicAdd(&stats[(bm * 8 + tid) * 2 + 1], a2);
  }
}

// ---- GN1-apply + SiLU + pw conv1x1 (in place on Y) + GN2 stats -------------
__global__ __launch_bounds__(256) void k_pw(float* __restrict__ Y, const float* __restrict__ pw,
                                            const float* __restrict__ g1,
                                            const float* __restrict__ b1,
                                            const float* __restrict__ s1,
                                            float* __restrict__ s2) {
  __shared__ float PWT[4096];     // [c][o]
  __shared__ float HB[4][256];    // per wave: [lane][4 pixels]
  __shared__ float red_s[256], red_ss[256];
  int tid = threadIdx.x, lane = tid & 63, wv = tid >> 6;
  int bm = blockIdx.x >> 2, pt = blockIdx.x & 3;
  int b = bm >> 3, m = bm & 7;
  int n0 = pt * 256;
  for (int i = tid; i < 4096; i += 256) {
    int o = i >> 6, c = i & 63;
    PWT[c * 64 + o] = pw[i];
  }
  int g = lane >> 3;
  float sg = s1[(bm * 8 + g) * 2], sg2 = s1[(bm * 8 + g) * 2 + 1];
  float mean = sg * (1.f / 8192.f);
  float var = sg2 * (1.f / 8192.f) - mean * mean;
  float rstd = rsqrtf(var + 1e-5f);
  float A = rstd * g1[lane];
  float Bc = b1[lane] - mean * A;
  __syncthreads();
  float st = 0.f, st2 = 0.f;
  const size_t base = (size_t)b * 1024 * 512 + (size_t)m * 64 + lane;
  for (int it = 0; it < 16; ++it) {
    int n = n0 + it * 16 + wv * 4;
    float h[4];
#pragma unroll
    for (int jj = 0; jj < 4; ++jj) {
      float y = Y[base + (size_t)(n + jj) * 512];
      h[jj] = silu_f(y * A + Bc);
    }
    *(float4*)&HB[wv][lane * 4] = make_float4(h[0], h[1], h[2], h[3]);
    __asm__ volatile("" ::: "memory");
    float a0 = 0.f, a1 = 0.f, a2 = 0.f, a3 = 0.f;
#pragma unroll 8
    for (int c = 0; c < 64; ++c) {
      float4 hh = *(const float4*)&HB[wv][c * 4];
      float w = PWT[c * 64 + lane];
      a0 += hh.x * w; a1 += hh.y * w; a2 += hh.z * w; a3 += hh.w * w;
    }
    float vals[4] = {a0, a1, a2, a3};
#pragma unroll
    for (int jj = 0; jj < 4; ++jj) {
      Y[base + (size_t)(n + jj) * 512] = vals[jj];
      st += vals[jj];
      st2 += vals[jj] * vals[jj];
    }
    __asm__ volatile("" ::: "memory");
  }
  red_s[tid] = st;
  red_ss[tid] = st2;
  __syncthreads();
  if (tid < 8) {
    float a = 0.f, a2 = 0.f;
    for (int w4 = 0; w4 < 4; ++w4)
      for (int j = 0; j < 8; ++j) {
        int t2 = w4 * 64 + tid * 8 + j;
        a += red_s[t2]; a2 += red_ss[t2];
      }
    atomicAdd(&s2[(bm * 8 + tid) * 2 + 0], a);
    atomicAdd(&s2[(bm * 8 + tid) * 2 + 1], a2);
  }
}

// ---- GN2-apply + residual + SiLU + present mask -> X -----------------------
__global__ __launch_bounds__(256) void k_fuse(const float* __restrict__ T,
                                              const float* __restrict__ Y,
                                              float* __restrict__ X,
                                              const float* __restrict__ g2,
                                              const float* __restrict__ b2,
                                              const float* __restrict__ s2,
                                              const float* __restrict__ present) {
  int tid = threadIdx.x, lane = tid & 63, wv = tid >> 6;
  int bm = blockIdx.x >> 3, pt = blockIdx.x & 7;
  int b = bm >> 3, m = bm & 7;
  int g = lane >> 3;
  float sg = s2[(bm * 8 + g) * 2], sg2 = s2[(bm * 8 + g) * 2 + 1];
  float mean = sg * (1.f / 8192.f);
  float var = sg2 * (1.f / 8192.f) - mean * mean;
  float rstd = rsqrtf(var + 1e-5f);
  float A = rstd * g2[lane];
  float Bc = b2[lane] - mean * A;
  float pres = present[bm];
  const size_t base = (size_t)b * 1024 * 512 + (size_t)m * 64 + lane;
  int n0 = pt * 128;
  for (int i2 = 0; i2 < 32; ++i2) {
    int n = n0 + i2 * 4 + wv;
    size_t idx = base + (size_t)n * 512;
    float z = T[idx] + (Y[idx] * A + Bc);
    X[idx] = silu_f(z) * pres;
  }
}

// ---- heads: policy logits + opp_move ---------------------------------------
__global__ __launch_bounds__(256) void k_heads_px(const float* __restrict__ X,
                                                  const float* __restrict__ pol_w,
                                                  const float* __restrict__ pol_b,
                                                  const float* __restrict__ om_w,
                                                  const float* __restrict__ om_b,
                                                  const float* __restrict__ present,
                                                  float* __restrict__ out) {
  int tid = threadIdx.x, lane = tid & 63, wv = tid >> 6;
  int b = blockIdx.x >> 4, n0 = (blockIdx.x & 15) * 64;
  float pw_ = pol_w[lane];
  for (int it = 0; it < 16; ++it) {
    int n = n0 + wv * 16 + it;
    const float* xp = X + ((size_t)(b * 1024 + n) * 8) * 64 + lane;
#pragma unroll
    for (int m = 0; m < 8; ++m) {
      float v = xp[m * 64];
      float d = wsum64(v * om_w[m * 64 + lane]);
      if (m == 0) {
        float dp = wsum64(v * pw_);
        if (lane == 0) out[b * 1024 + n] = dp + pol_b[0];
      }
      if (lane == 0)
        out[16400u + (size_t)(b * 8 + m) * 1024 + n] = (d + om_b[m]) * present[b * 8 + m];
    }
  }
}

// ---- heads: spatial mean pool ----------------------------------------------
__global__ __launch_bounds__(256) void k_pool(const float* __restrict__ X,
                                              float* __restrict__ pooled) {
  __shared__ float red[256];
  int tid = threadIdx.x, lane = tid & 63, wv = tid >> 6;
  int b = blockIdx.x >> 3, m = blockIdx.x & 7;
  float s = 0.f;
  for (int p = wv; p < 1024; p += 4)
    s += X[((size_t)(b * 1024 + p) * 8 + m) * 64 + lane];
  red[tid] = s;
  __syncthreads();
  if (tid < 64)
    pooled[(b * 8 + m) * 64 + tid] =
        (red[tid] + red[tid + 64] + red[tid + 128] + red[tid + 192]) * (1.f / 1024.f);
}

// ---- heads: value MLP + opp_param MLP --------------------------------------
__global__ __launch_bounds__(64) void k_heads_vec(
    const float* __restrict__ pooled, const float* __restrict__ vh_w1,
    const float* __restrict__ vh_b1, const float* __restrict__ vh_w2,
    const float* __restrict__ vh_b2, const float* __restrict__ op_w1,
    const float* __restrict__ op_b1, const float* __restrict__ op_w2,
    const float* __restrict__ op_b2, const float* __restrict__ present,
    float* __restrict__ out) {
  int lane = threadIdx.x;
  int b = blockIdx.x >> 3, m = blockIdx.x & 7;
  const float* pp = pooled + (b * 8 + m) * 64;
  float h = op_b1[lane];
  for (int c = 0; c < 64; ++c) h += pp[c] * op_w1[lane * 64 + c];
  h = silu_f(h);
  float pres = present[b * 8 + m];
  for (int jj = 0; jj < 5; ++jj) {
    float d = wsum64(h * op_w2[(m * 5 + jj) * 64 + lane]);
    if (lane == 0) out[147472u + (b * 8 + m) * 5 + jj] = (d + op_b2[m * 5 + jj]) * pres;
  }
  if (m == 0) {
    float hv = vh_b1[lane];
    for (int c = 0; c < 64; ++c) hv += pp[c] * vh_w1[lane * 64 + c];
    hv = silu_f(hv);
    float dv = wsum64(hv * vh_w2[lane]);
    if (lane == 0) out[16384u + b] = dv + vh_b2[0];
  }
}

// ---------------------------------------------------------------------------
extern "C" void kernel_launch(void* const* d_in, const int* in_sizes, int n_in,
                              void* d_out, int out_size, void* d_ws, size_t ws_size,
                              hipStream_t stream) {
  const float* board  = (const float*)d_in[0];
  const float* stem_w = (const float*)d_in[1];
  const float* stem_g = (const float*)d_in[2];
  const float* stem_b = (const float*)d_in[3];
  const float* qw = (const float*)d_in[4];
  const float* qb = (const float*)d_in[5];
  const float* kw = (const float*)d_in[6];
  const float* kb = (const float*)d_in[7];
  const float* vw = (const float*)d_in[8];
  const float* vb = (const float*)d_in[9];
  const float* ow = (const float*)d_in[10];
  const float* ob = (const float*)d_in[11];
  const float* ln_g = (const float*)d_in[12];
  const float* ln_b = (const float*)d_in[13];
  const float* dw_w = (const float*)d_in[14];
  const float* gn1_g = (const float*)d_in[15];
  const float* gn1_b = (const float*)d_in[16];
  const float* pw_w = (const float*)d_in[17];
  const float* gn2_g = (const float*)d_in[18];
  const float* gn2_b = (const float*)d_in[19];
  const float* pol_w = (const float*)d_in[20];
  const float* pol_b = (const float*)d_in[21];
  const float* vh_w1 = (const float*)d_in[22];
  const float* vh_b1 = (const float*)d_in[23];
  const float* vh_w2 = (const float*)d_in[24];
  const float* vh_b2 = (const float*)d_in[25];
  const float* om_w = (const float*)d_in[26];
  const float* om_b = (const float*)d_in[27];
  const float* op_w1 = (const float*)d_in[28];
  const float* op_b1 = (const float*)d_in[29];
  const float* op_w2 = (const float*)d_in[30];
  const float* op_b2 = (const float*)d_in[31];
  float* ws = (float*)d_ws;
  float* out = (float*)d_out;

  (void)hipFuncSetAttribute((const void*)k_attn,
                            hipFuncAttributeMaxDynamicSharedMemorySize,
                            ATTN_LDS_BYTES);

  k_init<<<64, 256, 0, stream>>>(board, ws);
  k_stem<<<256, 256, 0, stream>>>(board, stem_w, ws);
  k_gn_silu<<<2048, 256, 0, stream>>>(ws + WSX, stem_g, stem_b, ws + WSS);

  for (int i = 0; i < 6; ++i) {
    float* s1 = ws + WSS + (size_t)(1 + 2 * i) * 2048;
    float* s2 = ws + WSS + (size_t)(2 + 2 * i) * 2048;
    k_attn<<<512, 512, ATTN_LDS_BYTES, stream>>>(
        ws + WSX, ws + WST, qw + i * 4096, qb + i * 64, kw + i * 4096, kb + i * 64,
        vw + i * 4096, vb + i * 64, ow + i * 4096, ob + i * 64, ln_g + i * 64,
        ln_b + i * 64, ws + WSP);
    k_dw<<<1024, 256, 0, stream>>>(ws + WST, ws + WSY, dw_w + i * 576, s1);
    k_pw<<<512, 256, 0, stream>>>(ws + WSY, pw_w + i * 4096, gn1_g + i * 64,
                                  gn1_b + i * 64, s1, s2);
    k_fuse<<<1024, 256, 0, stream>>>(ws + WST, ws + WSY, ws + WSX, gn2_g + i * 64,
                                     gn2_b + i * 64, s2, ws + WSP);
  }

  k_heads_px<<<256, 256, 0, stream>>>(ws + WSX, pol_w, pol_b, om_w, om_b, ws + WSP, out);
  k_pool<<<128, 256, 0, stream>>>(ws + WSX, ws + WSPL);
  k_heads_vec<<<128, 64, 0, stream>>>(ws + WSPL, vh_w1, vh_b1, vh_w2, vh_b2, op_w1,
                                      op_b1, op_w2, op_b2, ws + WSP, out);
}

// Round 11
// 1547.841 us; speedup vs baseline: 1.2003x; 1.0868x over previous
//
#include <hip/hip_runtime.h>
#include <cstddef>

// ---------------------------------------------------------------------------
// PolicyValueDWPixelPlayerAttnNoFFNNet — fp32, round 8 (resubmit: R9/R10 infra fail)
// Layout: [b][n=h*32+w][m][c], c fastest.
// R8: (1) k_attn O-projection broadcast via LDS BUF (idle pipe) + v_rcp;
//     (2) GN2+residual+SiLU of layer i-1 fused into k_attn prologue
//         (layers 1-5) — k_fuse runs only once, after layer 5.
// ---------------------------------------------------------------------------

#define WSX   0u
#define WST   8388608u
#define WSY   16777216u
#define WSS   25165824u
#define WSP   (WSS + 26624u)
#define WSPL  (WSP + 128u)

#define ATTN_LDS_BYTES ((4 * 64 * 64 + 8 * 64 * 8) * 4)  // 64KB W + 16KB BUF

__device__ __forceinline__ float silu_f(float x) { return x / (1.f + __expf(-x)); }

__device__ __forceinline__ float wsum64(float v) {
#pragma unroll
  for (int s = 1; s < 64; s <<= 1) v += __shfl_xor(v, s);
  return v;
}

// broadcast lane l's value to all lanes (VALU, no LDS)
__device__ __forceinline__ float bcastlane(float v, int l) {
  return __int_as_float(__builtin_amdgcn_readlane(__float_as_int(v), l));
}

// sum within each 16-lane DPP row (VALU, no LDS): ror 8,4,2,1
__device__ __forceinline__ float rowsum16(float v) {
  v += __int_as_float(__builtin_amdgcn_update_dpp(0, __float_as_int(v), 0x128, 0xf, 0xf, true));
  v += __int_as_float(__builtin_amdgcn_update_dpp(0, __float_as_int(v), 0x124, 0xf, 0xf, true));
  v += __int_as_float(__builtin_amdgcn_update_dpp(0, __float_as_int(v), 0x122, 0xf, 0xf, true));
  v += __int_as_float(__builtin_amdgcn_update_dpp(0, __float_as_int(v), 0x121, 0xf, 0xf, true));
  return v;
}

// full 64-lane sum: DPP within rows, shfl across rows (2 LDS ops)
__device__ __forceinline__ float wsum64b(float v) {
  v = rowsum16(v);
  v += __shfl_xor(v, 16);
  v += __shfl_xor(v, 32);
  return v;
}

// ---- init: zero stats, compute present mask --------------------------------
__global__ __launch_bounds__(256) void k_init(const float* __restrict__ board,
                                              float* __restrict__ ws) {
  int tid = threadIdx.x;
  for (unsigned i = blockIdx.x * 256 + tid; i < 26624u; i += 64u * 256u) ws[WSS + i] = 0.f;
  if (blockIdx.x == 0 && tid < 128) {
    int b = tid >> 3, m = tid & 7;
    float best = board[(size_t)(b * 149 + 7) * 1024];
    int bi = 0;
    for (int ch = 1; ch < 7; ++ch) {
      float v = board[(size_t)(b * 149 + 7 + ch) * 1024];
      if (v > best) { best = v; bi = ch; }
    }
    int m_each = bi + 2;  // 2..8
    ws[WSP + tid] = (m < m_each) ? 1.f : 0.f;
  }
}

// ---- stem: conv1x1 (35->64) into X + GN stats ------------------------------
__global__ __launch_bounds__(256) void k_stem(const float* __restrict__ board,
                                              const float* __restrict__ stem_w,
                                              float* __restrict__ ws) {
  __shared__ float A[147 * 64];   // [ch][pix]
  __shared__ float WT[35 * 64];   // [c][o]
  __shared__ float red_s[256], red_ss[256];
  int tid = threadIdx.x;
  int b = blockIdx.x >> 4, n0 = (blockIdx.x & 15) * 64;
  for (int i = tid; i < 147 * 64; i += 256) {
    int c = i >> 6, p = i & 63;
    A[i] = board[(size_t)(b * 149 + c) * 1024 + n0 + p];
  }
  for (int i = tid; i < 35 * 64; i += 256) {
    int o = i / 35, c = i % 35;
    WT[c * 64 + o] = stem_w[i];
  }
  __syncthreads();
  int o = tid & 63, wv = tid >> 6;
  float* X = ws + WSX;
  float st_s[8], st_ss[8];
#pragma unroll
  for (int m = 0; m < 8; ++m) { st_s[m] = 0.f; st_ss[m] = 0.f; }
  for (int m = 0; m < 8; ++m) {
    for (int k = 0; k < 4; ++k) {
      int q = wv + 4 * k;
      float a0 = 0.f, a1 = 0.f, a2 = 0.f, a3 = 0.f;
#pragma unroll
      for (int c = 0; c < 19; ++c) {
        float w = WT[c * 64 + o];
        float4 av = *(const float4*)&A[c * 64 + q * 4];
        a0 += av.x * w; a1 += av.y * w; a2 += av.z * w; a3 += av.w * w;
      }
#pragma unroll
      for (int j = 0; j < 16; ++j) {
        float w = WT[(19 + j) * 64 + o];
        float4 av = *(const float4*)&A[(19 + m * 16 + j) * 64 + q * 4];
        a0 += av.x * w; a1 += av.y * w; a2 += av.z * w; a3 += av.w * w;
      }
      int n = n0 + q * 4;
      float vals[4] = {a0, a1, a2, a3};
#pragma unroll
      for (int j = 0; j < 4; ++j) {
        X[((size_t)(b * 1024 + n + j) * 8 + m) * 64 + o] = vals[j];
        st_s[m] += vals[j];
        st_ss[m] += vals[j] * vals[j];
      }
    }
  }
  float* stats = ws + WSS;
  for (int m = 0; m < 8; ++m) {
    __syncthreads();
    red_s[tid] = st_s[m];
    red_ss[tid] = st_ss[m];
    __syncthreads();
    if (tid < 8) {
      float a = 0.f, a2 = 0.f;
      for (int w4 = 0; w4 < 4; ++w4)
        for (int j = 0; j < 8; ++j) {
          int t2 = w4 * 64 + tid * 8 + j;
          a += red_s[t2]; a2 += red_ss[t2];
        }
      atomicAdd(&stats[((b * 8 + m) * 8 + tid) * 2 + 0], a);
      atomicAdd(&stats[((b * 8 + m) * 8 + tid) * 2 + 1], a2);
    }
  }
}

// ---- apply GN (+weights) + SiLU in place on X (stem only) ------------------
__global__ __launch_bounds__(256) void k_gn_silu(float* __restrict__ X,
                                                 const float* __restrict__ g,
                                                 const float* __restrict__ bt,
                                                 const float* __restrict__ stats) {
  for (size_t idx = (size_t)blockIdx.x * 256 + threadIdx.x; idx < 8388608ull;
       idx += (size_t)2048 * 256) {
    int c = (int)(idx & 63);
    int m = (int)((idx >> 6) & 7);
    int b = (int)(idx >> 19);
    int gi = ((b * 8 + m) * 8 + (c >> 3)) * 2;
    float s = stats[gi], s2 = stats[gi + 1];
    float mean = s * (1.f / 8192.f);
    float var = s2 * (1.f / 8192.f) - mean * mean;
    float rstd = rsqrtf(var + 1e-5f);
    float v = (X[idx] - mean) * rstd * g[c] + bt[c];
    X[idx] = silu_f(v);
  }
}

// ---- fused per-pixel attention + residual + LayerNorm ----------------------
// fused=1: tok = silu(Tin + GN2(Yin))*pres  (layer i-1 epilogue folded in)
#define FMA8(acc, WW)                                                      \
  acc[0] += t0.x * (WW); acc[1] += t0.y * (WW); acc[2] += t0.z * (WW);     \
  acc[3] += t0.w * (WW); acc[4] += t1.x * (WW); acc[5] += t1.y * (WW);     \
  acc[6] += t1.z * (WW); acc[7] += t1.w * (WW);

__global__ __launch_bounds__(512, 4) void k_attn(
    const float* __restrict__ Xin, const float* __restrict__ Yin,
    const float* __restrict__ s2p, const float* __restrict__ g2p,
    const float* __restrict__ b2p, float* __restrict__ T,
    const float* __restrict__ qw, const float* __restrict__ qb,
    const float* __restrict__ kw, const float* __restrict__ kb,
    const float* __restrict__ vw, const float* __restrict__ vb,
    const float* __restrict__ ow, const float* __restrict__ ob,
    const float* __restrict__ lng, const float* __restrict__ lnb,
    const float* __restrict__ present, int fused) {
  extern __shared__ float sm[];
  float* Wq = sm;              // [c][o]
  float* Wk = sm + 4096;
  float* Wv = sm + 8192;
  float* Wo = sm + 12288;
  float* BUF = sm + 16384;     // per-wave 512-float staging for O broadcast
  int tid = threadIdx.x;
  int lane = tid & 63, wv = tid >> 6;              // wv 0..7
  int b = blockIdx.x >> 5;
  int n0 = (blockIdx.x & 31) * 32;
  for (int i = tid; i < 4096; i += 512) {
    int o = i >> 6, c = i & 63;
    Wq[c * 64 + o] = qw[i];
    Wk[c * 64 + o] = kw[i];
    Wv[c * 64 + o] = vw[i];
    Wo[c * 64 + o] = ow[i];
  }
  float bq = qb[lane], bk = kb[lane], bv = vb[lane], bo = ob[lane];
  float gl = lng[lane], bl = lnb[lane];
  unsigned pmask = 0;
#pragma unroll
  for (int m = 0; m < 8; ++m) pmask |= (present[b * 8 + m] > 0.5f) ? (1u << m) : 0u;
  // GN2 affine constants of previous layer (fused mode)
  float Ag[8], Bg[8];
  if (fused) {
    int g = lane >> 3;
    float gw = g2p[lane], bw_ = b2p[lane];
#pragma unroll
    for (int m = 0; m < 8; ++m) {
      int gi = ((b * 8 + m) * 8 + g) * 2;
      float sg = s2p[gi], sg2 = s2p[gi + 1];
      float mean = sg * (1.f / 8192.f);
      float var = sg2 * (1.f / 8192.f) - mean * mean;
      float rstd = rsqrtf(var + 1e-5f);
      Ag[m] = rstd * gw;
      Bg[m] = bw_ - mean * Ag[m];
    }
  }
  __syncthreads();
  float* bw = BUF + wv * 512;
  const int sw = lane & 12;
  for (int j = 0; j < 4; ++j) {
    int n = n0 + wv * 4 + j;
    size_t pbase = ((size_t)(b * 1024 + n) * 8) * 64 + lane;
    float tok[8];
    if (fused) {
#pragma unroll
      for (int m = 0; m < 8; ++m) {
        float tv = Xin[pbase + m * 64];
        float yv = Yin[pbase + m * 64];
        float z = tv + (yv * Ag[m] + Bg[m]);
        float pres = ((pmask >> m) & 1) ? 1.f : 0.f;
        tok[m] = silu_f(z) * pres;
      }
    } else {
#pragma unroll
      for (int m = 0; m < 8; ++m) tok[m] = Xin[pbase + m * 64];
    }
    // qkv projections: token broadcast via readlane (VALU)
    float aq[8], ak[8], av[8];
#pragma unroll
    for (int m = 0; m < 8; ++m) { aq[m] = bq; ak[m] = bk; av[m] = bv; }
#pragma unroll 16
    for (int c = 0; c < 64; ++c) {
      float wq_ = Wq[c * 64 + lane];
      float wk_ = Wk[c * 64 + lane];
      float wv_ = Wv[c * 64 + lane];
#pragma unroll
      for (int m = 0; m < 8; ++m) {
        float t = bcastlane(tok[m], c);
        aq[m] = fmaf(t, wq_, aq[m]);
        ak[m] = fmaf(t, wk_, ak[m]);
        av[m] = fmaf(t, wv_, av[m]);
      }
    }
    // attention: lane holds channel o; head = o>>4; DPP row sums
    float ao[8];
#pragma unroll
    for (int mq = 0; mq < 8; ++mq) {
      float lg[8];
#pragma unroll
      for (int mk = 0; mk < 8; ++mk)
        lg[mk] = rowsum16(aq[mq] * ak[mk]) * 0.25f;
      float mx = -3.0e38f;
#pragma unroll
      for (int mk = 0; mk < 8; ++mk)
        if ((pmask >> mk) & 1) mx = fmaxf(mx, lg[mk]);
      float se = 0.f, acc = 0.f;
#pragma unroll
      for (int mk = 0; mk < 8; ++mk) {
        float e = ((pmask >> mk) & 1) ? __expf(lg[mk] - mx) : 0.f;
        se += e;
        acc += e * av[mk];
      }
      ao[mq] = acc * __builtin_amdgcn_rcpf(se);
    }
    // o-projection: broadcast via LDS (idle pipe) — stage ao, uniform reads
    *(float4*)&bw[(lane * 8) ^ sw]     = make_float4(ao[0], ao[1], ao[2], ao[3]);
    *(float4*)&bw[(lane * 8 + 4) ^ sw] = make_float4(ao[4], ao[5], ao[6], ao[7]);
    __asm__ volatile("" ::: "memory");
    float z[8];
#pragma unroll
    for (int m = 0; m < 8; ++m) z[m] = bo;
#pragma unroll 16
    for (int c = 0; c < 64; ++c) {
      float4 t0 = *(const float4*)&bw[(c * 8) ^ (c & 12)];
      float4 t1 = *(const float4*)&bw[(c * 8 + 4) ^ (c & 12)];
      float wo_ = Wo[c * 64 + lane];
      FMA8(z, wo_)
    }
    __asm__ volatile("" ::: "memory");
    // residual + LayerNorm
    float* tp = T + pbase;
#pragma unroll
    for (int m = 0; m < 8; ++m) {
      float r = tok[m] + z[m];
      float mean = wsum64b(r) * (1.f / 64.f);
      float d = r - mean;
      float var = wsum64b(d * d) * (1.f / 64.f);
      float rstd = rsqrtf(var + 1e-5f);
      tp[m * 64] = d * rstd * gl + bl;
    }
  }
}

// ---- depthwise 3x3 (SAME, zero pad) + GN1 stats ----------------------------
__global__ __launch_bounds__(256) void k_dw(const float* __restrict__ T, float* __restrict__ Y,
                                            const float* __restrict__ dww,
                                            float* __restrict__ stats) {
  __shared__ float red_s[256], red_ss[256];
  int tid = threadIdx.x, lane = tid & 63, wv = tid >> 6;
  int bm = blockIdx.x >> 3, rg = blockIdx.x & 7;
  int b = bm >> 3, m = bm & 7;
  int r = rg * 4 + wv;
  float w9[9];
#pragma unroll
  for (int k = 0; k < 9; ++k) w9[k] = dww[lane * 9 + k];
  float s = 0.f, ss = 0.f;
  const size_t base = (size_t)b * 1024 * 512 + (size_t)m * 64 + lane;
  for (int col = 0; col < 32; ++col) {
    float acc = 0.f;
#pragma unroll
    for (int dh = -1; dh <= 1; ++dh) {
      int rr = r + dh;
      if (rr < 0 || rr > 31) continue;
#pragma unroll
      for (int dx = -1; dx <= 1; ++dx) {
        int cc = col + dx;
        if (cc < 0 || cc > 31) continue;
        acc += T[base + (size_t)(rr * 32 + cc) * 512] * w9[(dh + 1) * 3 + dx + 1];
      }
    }
    Y[base + (size_t)(r * 32 + col) * 512] = acc;
    s += acc;
    ss += acc * acc;
  }
  red_s[tid] = s;
  red_ss[tid] = ss;
  __syncthreads();
  if (tid < 8) {
    float a = 0.f, a2 = 0.f;
    for (int w4 = 0; w4 < 4; ++w4)
      for (int j = 0; j < 8; ++j) {
        int t2 = w4 * 64 + tid * 8 + j;
        a += red_s[t2]; a2 += red_ss[t2];
      }
    atomicAdd(&stats[(bm * 8 + tid) * 2 + 0], a);
    atomicAdd(&stats[(bm * 8 + tid) * 2 + 1], a2);
  }
}

// ---- GN1-apply + SiLU + pw conv1x1 (in place on Y) + GN2 stats -------------
__global__ __launch_bounds__(256) void k_pw(float* __restrict__ Y, const float* __restrict__ pw,
                                            const float* __restrict__ g1,
                                            const float* __restrict__ b1,
                                            const float* __restrict__ s1,
                                            float* __restrict__ s2) {
  __shared__ float PWT[4096];
  __shared__ float HB[4][256];
  __shared__ float red_s[256], red_ss[256];
  int tid = threadIdx.x, lane = tid & 63, wv = tid >> 6;
  int bm = blockIdx.x >> 2, pt = blockIdx.x & 3;
  int b = bm >> 3, m = bm & 7;
  int n0 = pt * 256;
  for (int i = tid; i < 4096; i += 256) {
    int o = i >> 6, c = i & 63;
    PWT[c * 64 + o] = pw[i];
  }
  int g = lane >> 3;
  float sg = s1[(bm * 8 + g) * 2], sg2 = s1[(bm * 8 + g) * 2 + 1];
  float mean = sg * (1.f / 8192.f);
  float var = sg2 * (1.f / 8192.f) - mean * mean;
  float rstd = rsqrtf(var + 1e-5f);
  float A = rstd * g1[lane];
  float Bc = b1[lane] - mean * A;
  __syncthreads();
  float st = 0.f, st2 = 0.f;
  const size_t base = (size_t)b * 1024 * 512 + (size_t)m * 64 + lane;
  for (int it = 0; it < 16; ++it) {
    int n = n0 + it * 16 + wv * 4;
    float h[4];
#pragma unroll
    for (int jj = 0; jj < 4; ++jj) {
      float y = Y[base + (size_t)(n + jj) * 512];
      h[jj] = silu_f(y * A + Bc);
    }
    *(float4*)&HB[wv][lane * 4] = make_float4(h[0], h[1], h[2], h[3]);
    __asm__ volatile("" ::: "memory");
    float a0 = 0.f, a1 = 0.f, a2 = 0.f, a3 = 0.f;
#pragma unroll 8
    for (int c = 0; c < 64; ++c) {
      float4 hh = *(const float4*)&HB[wv][c * 4];
      float w = PWT[c * 64 + lane];
      a0 += hh.x * w; a1 += hh.y * w; a2 += hh.z * w; a3 += hh.w * w;
    }
    float vals[4] = {a0, a1, a2, a3};
#pragma unroll
    for (int jj = 0; jj < 4; ++jj) {
      Y[base + (size_t)(n + jj) * 512] = vals[jj];
      st += vals[jj];
      st2 += vals[jj] * vals[jj];
    }
    __asm__ volatile("" ::: "memory");
  }
  red_s[tid] = st;
  red_ss[tid] = st2;
  __syncthreads();
  if (tid < 8) {
    float a = 0.f, a2 = 0.f;
    for (int w4 = 0; w4 < 4; ++w4)
      for (int j = 0; j < 8; ++j) {
        int t2 = w4 * 64 + tid * 8 + j;
        a += red_s[t2]; a2 += red_ss[t2];
      }
    atomicAdd(&s2[(bm * 8 + tid) * 2 + 0], a);
    atomicAdd(&s2[(bm * 8 + tid) * 2 + 1], a2);
  }
}

// ---- GN2-apply + residual + SiLU + present mask -> X (final layer only) ----
__global__ __launch_bounds__(256) void k_fuse(const float* __restrict__ T,
                                              const float* __restrict__ Y,
                                              float* __restrict__ X,
                                              const float* __restrict__ g2,
                                              const float* __restrict__ b2,
                                              const float* __restrict__ s2,
                                              const float* __restrict__ present) {
  int tid = threadIdx.x, lane = tid & 63, wv = tid >> 6;
  int bm = blockIdx.x >> 3, pt = blockIdx.x & 7;
  int b = bm >> 3, m = bm & 7;
  int g = lane >> 3;
  float sg = s2[(bm * 8 + g) * 2], sg2 = s2[(bm * 8 + g) * 2 + 1];
  float mean = sg * (1.f / 8192.f);
  float var = sg2 * (1.f / 8192.f) - mean * mean;
  float rstd = rsqrtf(var + 1e-5f);
  float A = rstd * g2[lane];
  float Bc = b2[lane] - mean * A;
  float pres = present[bm];
  const size_t base = (size_t)b * 1024 * 512 + (size_t)m * 64 + lane;
  int n0 = pt * 128;
  for (int i2 = 0; i2 < 32; ++i2) {
    int n = n0 + i2 * 4 + wv;
    size_t idx = base + (size_t)n * 512;
    float z = T[idx] + (Y[idx] * A + Bc);
    X[idx] = silu_f(z) * pres;
  }
}

// ---- heads: policy logits + opp_move ---------------------------------------
__global__ __launch_bounds__(256) void k_heads_px(const float* __restrict__ X,
                                                  const float* __restrict__ pol_w,
                                                  const float* __restrict__ pol_b,
                                                  const float* __restrict__ om_w,
                                                  const float* __restrict__ om_b,
                                                  const float* __restrict__ present,
                                                  float* __restrict__ out) {
  int tid = threadIdx.x, lane = tid & 63, wv = tid >> 6;
  int b = blockIdx.x >> 4, n0 = (blockIdx.x & 15) * 64;
  float pw_ = pol_w[lane];
  for (int it = 0; it < 16; ++it) {
    int n = n0 + wv * 16 + it;
    const float* xp = X + ((size_t)(b * 1024 + n) * 8) * 64 + lane;
#pragma unroll
    for (int m = 0; m < 8; ++m) {
      float v = xp[m * 64];
      float d = wsum64(v * om_w[m * 64 + lane]);
      if (m == 0) {
        float dp = wsum64(v * pw_);
        if (lane == 0) out[b * 1024 + n] = dp + pol_b[0];
      }
      if (lane == 0)
        out[16400u + (size_t)(b * 8 + m) * 1024 + n] = (d + om_b[m]) * present[b * 8 + m];
    }
  }
}

// ---- heads: spatial mean pool ----------------------------------------------
__global__ __launch_bounds__(256) void k_pool(const float* __restrict__ X,
                                              float* __restrict__ pooled) {
  __shared__ float red[256];
  int tid = threadIdx.x, lane = tid & 63, wv = tid >> 6;
  int b = blockIdx.x >> 3, m = blockIdx.x & 7;
  float s = 0.f;
  for (int p = wv; p < 1024; p += 4)
    s += X[((size_t)(b * 1024 + p) * 8 + m) * 64 + lane];
  red[tid] = s;
  __syncthreads();
  if (tid < 64)
    pooled[(b * 8 + m) * 64 + tid] =
        (red[tid] + red[tid + 64] + red[tid + 128] + red[tid + 192]) * (1.f / 1024.f);
}

// ---- heads: value MLP + opp_param MLP --------------------------------------
__global__ __launch_bounds__(64) void k_heads_vec(
    const float* __restrict__ pooled, const float* __restrict__ vh_w1,
    const float* __restrict__ vh_b1, const float* __restrict__ vh_w2,
    const float* __restrict__ vh_b2, const float* __restrict__ op_w1,
    const float* __restrict__ op_b1, const float* __restrict__ op_w2,
    const float* __restrict__ op_b2, const float* __restrict__ present,
    float* __restrict__ out) {
  int lane = threadIdx.x;
  int b = blockIdx.x >> 3, m = blockIdx.x & 7;
  const float* pp = pooled + (b * 8 + m) * 64;
  float h = op_b1[lane];
  for (int c = 0; c < 64; ++c) h += pp[c] * op_w1[lane * 64 + c];
  h = silu_f(h);
  float pres = present[b * 8 + m];
  for (int jj = 0; jj < 5; ++jj) {
    float d = wsum64(h * op_w2[(m * 5 + jj) * 64 + lane]);
    if (lane == 0) out[147472u + (b * 8 + m) * 5 + jj] = (d + op_b2[m * 5 + jj]) * pres;
  }
  if (m == 0) {
    float hv = vh_b1[lane];
    for (int c = 0; c < 64; ++c) hv += pp[c] * vh_w1[lane * 64 + c];
    hv = silu_f(hv);
    float dv = wsum64(hv * vh_w2[lane]);
    if (lane == 0) out[16384u + b] = dv + vh_b2[0];
  }
}

// ---------------------------------------------------------------------------
extern "C" void kernel_launch(void* const* d_in, const int* in_sizes, int n_in,
                              void* d_out, int out_size, void* d_ws, size_t ws_size,
                              hipStream_t stream) {
  const float* board  = (const float*)d_in[0];
  const float* stem_w = (const float*)d_in[1];
  const float* stem_g = (const float*)d_in[2];
  const float* stem_b = (const float*)d_in[3];
  const float* qw = (const float*)d_in[4];
  const float* qb = (const float*)d_in[5];
  const float* kw = (const float*)d_in[6];
  const float* kb = (const float*)d_in[7];
  const float* vw = (const float*)d_in[8];
  const float* vb = (const float*)d_in[9];
  const float* ow = (const float*)d_in[10];
  const float* ob = (const float*)d_in[11];
  const float* ln_g = (const float*)d_in[12];
  const float* ln_b = (const float*)d_in[13];
  const float* dw_w = (const float*)d_in[14];
  const float* gn1_g = (const float*)d_in[15];
  const float* gn1_b = (const float*)d_in[16];
  const float* pw_w = (const float*)d_in[17];
  const float* gn2_g = (const float*)d_in[18];
  const float* gn2_b = (const float*)d_in[19];
  const float* pol_w = (const float*)d_in[20];
  const float* pol_b = (const float*)d_in[21];
  const float* vh_w1 = (const float*)d_in[22];
  const float* vh_b1 = (const float*)d_in[23];
  const float* vh_w2 = (const float*)d_in[24];
  const float* vh_b2 = (const float*)d_in[25];
  const float* om_w = (const float*)d_in[26];
  const float* om_b = (const float*)d_in[27];
  const float* op_w1 = (const float*)d_in[28];
  const float* op_b1 = (const float*)d_in[29];
  const float* op_w2 = (const float*)d_in[30];
  const float* op_b2 = (const float*)d_in[31];
  float* ws = (float*)d_ws;
  float* out = (float*)d_out;

  (void)hipFuncSetAttribute((const void*)k_attn,
                            hipFuncAttributeMaxDynamicSharedMemorySize,
                            ATTN_LDS_BYTES);

  k_init<<<64, 256, 0, stream>>>(board, ws);
  k_stem<<<256, 256, 0, stream>>>(board, stem_w, ws);
  k_gn_silu<<<2048, 256, 0, stream>>>(ws + WSX, stem_g, stem_b, ws + WSS);

  for (int i = 0; i < 6; ++i) {
    float* s1 = ws + WSS + (size_t)(1 + 2 * i) * 2048;
    float* s2 = ws + WSS + (size_t)(2 + 2 * i) * 2048;
    if (i == 0) {
      k_attn<<<512, 512, ATTN_LDS_BYTES, stream>>>(
          ws + WSX, ws + WSX, ws + WSS, gn2_g, gn2_b, ws + WST,
          qw, qb, kw, kb, vw, vb, ow, ob, ln_g, ln_b, ws + WSP, 0);
    } else {
      float* s2prev = ws + WSS + (size_t)(2 * i) * 2048;  // layer i-1's GN2 stats
      k_attn<<<512, 512, ATTN_LDS_BYTES, stream>>>(
          ws + WST, ws + WSY, s2prev, gn2_g + (i - 1) * 64, gn2_b + (i - 1) * 64,
          ws + WST, qw + i * 4096, qb + i * 64, kw + i * 4096, kb + i * 64,
          vw + i * 4096, vb + i * 64, ow + i * 4096, ob + i * 64, ln_g + i * 64,
          ln_b + i * 64, ws + WSP, 1);
    }
    k_dw<<<1024, 256, 0, stream>>>(ws + WST, ws + WSY, dw_w + i * 576, s1);
    k_pw<<<512, 256, 0, stream>>>(ws + WSY, pw_w + i * 4096, gn1_g + i * 64,
                                  gn1_b + i * 64, s1, s2);
  }
  // final layer epilogue -> X for heads
  k_fuse<<<1024, 256, 0, stream>>>(ws + WST, ws + WSY, ws + WSX, gn2_g + 5 * 64,
                                   gn2_b + 5 * 64, ws + WSS + (size_t)12 * 2048,
                                   ws + WSP);

  k_heads_px<<<256, 256, 0, stream>>>(ws + WSX, pol_w, pol_b, om_w, om_b, ws + WSP, out);
  k_pool<<<128, 256, 0, stream>>>(ws + WSX, ws + WSPL);
  k_heads_vec<<<128, 64, 0, stream>>>(ws + WSPL, vh_w1, vh_b1, vh_w2, vh_b2, op_w1,
                                      op_b1, op_w2, op_b2, ws + WSP, out);
}

// Round 12
// 1411.282 us; speedup vs baseline: 1.3164x; 1.0968x over previous
//
#include <hip/hip_runtime.h>
#include <cstddef>

// ---------------------------------------------------------------------------
// PolicyValueDWPixelPlayerAttnNoFFNNet — fp32, round 11
// Layout: [b][n=h*32+w][m][c], c fastest.
// R11: (1) k_attn QKV broadcast via LDS BUF uniform b128 reads (replaces 512
//          readlane chains/pixel); softmax stays on DPP, O-proj stays on LDS.
//      (2) k_dw rewritten float4-per-thread (4 channels): 4x fewer load
//          issues, 1024B/wave per tap.
// ---------------------------------------------------------------------------

#define WSX   0u
#define WST   8388608u
#define WSY   16777216u
#define WSS   25165824u
#define WSP   (WSS + 26624u)
#define WSPL  (WSP + 128u)

#define ATTN_LDS_BYTES ((4 * 64 * 64 + 8 * 64 * 8) * 4)  // 64KB W + 16KB BUF

__device__ __forceinline__ float silu_f(float x) { return x / (1.f + __expf(-x)); }

__device__ __forceinline__ float wsum64(float v) {
#pragma unroll
  for (int s = 1; s < 64; s <<= 1) v += __shfl_xor(v, s);
  return v;
}

// sum within each 16-lane DPP row (VALU, no LDS): ror 8,4,2,1
__device__ __forceinline__ float rowsum16(float v) {
  v += __int_as_float(__builtin_amdgcn_update_dpp(0, __float_as_int(v), 0x128, 0xf, 0xf, true));
  v += __int_as_float(__builtin_amdgcn_update_dpp(0, __float_as_int(v), 0x124, 0xf, 0xf, true));
  v += __int_as_float(__builtin_amdgcn_update_dpp(0, __float_as_int(v), 0x122, 0xf, 0xf, true));
  v += __int_as_float(__builtin_amdgcn_update_dpp(0, __float_as_int(v), 0x121, 0xf, 0xf, true));
  return v;
}

// full 64-lane sum: DPP within rows, shfl across rows (2 LDS ops)
__device__ __forceinline__ float wsum64b(float v) {
  v = rowsum16(v);
  v += __shfl_xor(v, 16);
  v += __shfl_xor(v, 32);
  return v;
}

// ---- init: zero stats, compute present mask --------------------------------
__global__ __launch_bounds__(256) void k_init(const float* __restrict__ board,
                                              float* __restrict__ ws) {
  int tid = threadIdx.x;
  for (unsigned i = blockIdx.x * 256 + tid; i < 26624u; i += 64u * 256u) ws[WSS + i] = 0.f;
  if (blockIdx.x == 0 && tid < 128) {
    int b = tid >> 3, m = tid & 7;
    float best = board[(size_t)(b * 149 + 7) * 1024];
    int bi = 0;
    for (int ch = 1; ch < 7; ++ch) {
      float v = board[(size_t)(b * 149 + 7 + ch) * 1024];
      if (v > best) { best = v; bi = ch; }
    }
    int m_each = bi + 2;  // 2..8
    ws[WSP + tid] = (m < m_each) ? 1.f : 0.f;
  }
}

// ---- stem: conv1x1 (35->64) into X + GN stats ------------------------------
__global__ __launch_bounds__(256) void k_stem(const float* __restrict__ board,
                                              const float* __restrict__ stem_w,
                                              float* __restrict__ ws) {
  __shared__ float A[147 * 64];   // [ch][pix]
  __shared__ float WT[35 * 64];   // [c][o]
  __shared__ float red_s[256], red_ss[256];
  int tid = threadIdx.x;
  int b = blockIdx.x >> 4, n0 = (blockIdx.x & 15) * 64;
  for (int i = tid; i < 147 * 64; i += 256) {
    int c = i >> 6, p = i & 63;
    A[i] = board[(size_t)(b * 149 + c) * 1024 + n0 + p];
  }
  for (int i = tid; i < 35 * 64; i += 256) {
    int o = i / 35, c = i % 35;
    WT[c * 64 + o] = stem_w[i];
  }
  __syncthreads();
  int o = tid & 63, wv = tid >> 6;
  float* X = ws + WSX;
  float st_s[8], st_ss[8];
#pragma unroll
  for (int m = 0; m < 8; ++m) { st_s[m] = 0.f; st_ss[m] = 0.f; }
  for (int m = 0; m < 8; ++m) {
    for (int k = 0; k < 4; ++k) {
      int q = wv + 4 * k;
      float a0 = 0.f, a1 = 0.f, a2 = 0.f, a3 = 0.f;
#pragma unroll
      for (int c = 0; c < 19; ++c) {
        float w = WT[c * 64 + o];
        float4 av = *(const float4*)&A[c * 64 + q * 4];
        a0 += av.x * w; a1 += av.y * w; a2 += av.z * w; a3 += av.w * w;
      }
#pragma unroll
      for (int j = 0; j < 16; ++j) {
        float w = WT[(19 + j) * 64 + o];
        float4 av = *(const float4*)&A[(19 + m * 16 + j) * 64 + q * 4];
        a0 += av.x * w; a1 += av.y * w; a2 += av.z * w; a3 += av.w * w;
      }
      int n = n0 + q * 4;
      float vals[4] = {a0, a1, a2, a3};
#pragma unroll
      for (int j = 0; j < 4; ++j) {
        X[((size_t)(b * 1024 + n + j) * 8 + m) * 64 + o] = vals[j];
        st_s[m] += vals[j];
        st_ss[m] += vals[j] * vals[j];
      }
    }
  }
  float* stats = ws + WSS;
  for (int m = 0; m < 8; ++m) {
    __syncthreads();
    red_s[tid] = st_s[m];
    red_ss[tid] = st_ss[m];
    __syncthreads();
    if (tid < 8) {
      float a = 0.f, a2 = 0.f;
      for (int w4 = 0; w4 < 4; ++w4)
        for (int j = 0; j < 8; ++j) {
          int t2 = w4 * 64 + tid * 8 + j;
          a += red_s[t2]; a2 += red_ss[t2];
        }
      atomicAdd(&stats[((b * 8 + m) * 8 + tid) * 2 + 0], a);
      atomicAdd(&stats[((b * 8 + m) * 8 + tid) * 2 + 1], a2);
    }
  }
}

// ---- apply GN (+weights) + SiLU in place on X (stem only) ------------------
__global__ __launch_bounds__(256) void k_gn_silu(float* __restrict__ X,
                                                 const float* __restrict__ g,
                                                 const float* __restrict__ bt,
                                                 const float* __restrict__ stats) {
  for (size_t idx = (size_t)blockIdx.x * 256 + threadIdx.x; idx < 8388608ull;
       idx += (size_t)2048 * 256) {
    int c = (int)(idx & 63);
    int m = (int)((idx >> 6) & 7);
    int b = (int)(idx >> 19);
    int gi = ((b * 8 + m) * 8 + (c >> 3)) * 2;
    float s = stats[gi], s2 = stats[gi + 1];
    float mean = s * (1.f / 8192.f);
    float var = s2 * (1.f / 8192.f) - mean * mean;
    float rstd = rsqrtf(var + 1e-5f);
    float v = (X[idx] - mean) * rstd * g[c] + bt[c];
    X[idx] = silu_f(v);
  }
}

// ---- fused per-pixel attention + residual + LayerNorm ----------------------
// fused=1: tok = silu(Tin + GN2(Yin))*pres  (layer i-1 epilogue folded in)
#define FMA8(acc, WW)                                                      \
  acc[0] += t0.x * (WW); acc[1] += t0.y * (WW); acc[2] += t0.z * (WW);     \
  acc[3] += t0.w * (WW); acc[4] += t1.x * (WW); acc[5] += t1.y * (WW);     \
  acc[6] += t1.z * (WW); acc[7] += t1.w * (WW);

__global__ __launch_bounds__(512, 4) void k_attn(
    const float* __restrict__ Xin, const float* __restrict__ Yin,
    const float* __restrict__ s2p, const float* __restrict__ g2p,
    const float* __restrict__ b2p, float* __restrict__ T,
    const float* __restrict__ qw, const float* __restrict__ qb,
    const float* __restrict__ kw, const float* __restrict__ kb,
    const float* __restrict__ vw, const float* __restrict__ vb,
    const float* __restrict__ ow, const float* __restrict__ ob,
    const float* __restrict__ lng, const float* __restrict__ lnb,
    const float* __restrict__ present, int fused) {
  extern __shared__ float sm[];
  float* Wq = sm;              // [c][o]
  float* Wk = sm + 4096;
  float* Wv = sm + 8192;
  float* Wo = sm + 12288;
  float* BUF = sm + 16384;     // per-wave 512-float staging (tok, then ao)
  int tid = threadIdx.x;
  int lane = tid & 63, wv = tid >> 6;              // wv 0..7
  int b = blockIdx.x >> 5;
  int n0 = (blockIdx.x & 31) * 32;
  for (int i = tid; i < 4096; i += 512) {
    int o = i >> 6, c = i & 63;
    Wq[c * 64 + o] = qw[i];
    Wk[c * 64 + o] = kw[i];
    Wv[c * 64 + o] = vw[i];
    Wo[c * 64 + o] = ow[i];
  }
  float bq = qb[lane], bk = kb[lane], bv = vb[lane], bo = ob[lane];
  float gl = lng[lane], bl = lnb[lane];
  unsigned pmask = 0;
#pragma unroll
  for (int m = 0; m < 8; ++m) pmask |= (present[b * 8 + m] > 0.5f) ? (1u << m) : 0u;
  // GN2 affine constants of previous layer (fused mode)
  float Ag[8], Bg[8];
  if (fused) {
    int g = lane >> 3;
    float gw = g2p[lane], bw_ = b2p[lane];
#pragma unroll
    for (int m = 0; m < 8; ++m) {
      int gi = ((b * 8 + m) * 8 + g) * 2;
      float sg = s2p[gi], sg2 = s2p[gi + 1];
      float mean = sg * (1.f / 8192.f);
      float var = sg2 * (1.f / 8192.f) - mean * mean;
      float rstd = rsqrtf(var + 1e-5f);
      Ag[m] = rstd * gw;
      Bg[m] = bw_ - mean * Ag[m];
    }
  }
  __syncthreads();
  float* bw = BUF + wv * 512;
  const int sw = lane & 12;
  for (int j = 0; j < 4; ++j) {
    int n = n0 + wv * 4 + j;
    size_t pbase = ((size_t)(b * 1024 + n) * 8) * 64 + lane;
    float tok[8];
    if (fused) {
#pragma unroll
      for (int m = 0; m < 8; ++m) {
        float tv = Xin[pbase + m * 64];
        float yv = Yin[pbase + m * 64];
        float z = tv + (yv * Ag[m] + Bg[m]);
        float pres = ((pmask >> m) & 1) ? 1.f : 0.f;
        tok[m] = silu_f(z) * pres;
      }
    } else {
#pragma unroll
      for (int m = 0; m < 8; ++m) tok[m] = Xin[pbase + m * 64];
    }
    // stage tokens for LDS broadcast (wave-private region, swizzled)
    *(float4*)&bw[(lane * 8) ^ sw]     = make_float4(tok[0], tok[1], tok[2], tok[3]);
    *(float4*)&bw[(lane * 8 + 4) ^ sw] = make_float4(tok[4], tok[5], tok[6], tok[7]);
    __asm__ volatile("" ::: "memory");
    // qkv projections: token broadcast via uniform-address LDS b128 reads
    float aq[8], ak[8], av[8];
#pragma unroll
    for (int m = 0; m < 8; ++m) { aq[m] = bq; ak[m] = bk; av[m] = bv; }
#pragma unroll
    for (int c = 0; c < 64; ++c) {
      float4 t0 = *(const float4*)&bw[(c * 8) ^ (c & 12)];
      float4 t1 = *(const float4*)&bw[(c * 8 + 4) ^ (c & 12)];
      float wq_ = Wq[c * 64 + lane];
      float wk_ = Wk[c * 64 + lane];
      float wv_ = Wv[c * 64 + lane];
      FMA8(aq, wq_)
      FMA8(ak, wk_)
      FMA8(av, wv_)
    }
    // attention: lane holds channel o; head = o>>4; DPP row sums
    float ao[8];
#pragma unroll
    for (int mq = 0; mq < 8; ++mq) {
      float lg[8];
#pragma unroll
      for (int mk = 0; mk < 8; ++mk)
        lg[mk] = rowsum16(aq[mq] * ak[mk]) * 0.25f;
      float mx = -3.0e38f;
#pragma unroll
      for (int mk = 0; mk < 8; ++mk)
        if ((pmask >> mk) & 1) mx = fmaxf(mx, lg[mk]);
      float se = 0.f, acc = 0.f;
#pragma unroll
      for (int mk = 0; mk < 8; ++mk) {
        float e = ((pmask >> mk) & 1) ? __expf(lg[mk] - mx) : 0.f;
        se += e;
        acc += e * av[mk];
      }
      ao[mq] = acc * __builtin_amdgcn_rcpf(se);
    }
    __asm__ volatile("" ::: "memory");
    // o-projection: broadcast via LDS (reuse the same wave-private region)
    *(float4*)&bw[(lane * 8) ^ sw]     = make_float4(ao[0], ao[1], ao[2], ao[3]);
    *(float4*)&bw[(lane * 8 + 4) ^ sw] = make_float4(ao[4], ao[5], ao[6], ao[7]);
    __asm__ volatile("" ::: "memory");
    float z[8];
#pragma unroll
    for (int m = 0; m < 8; ++m) z[m] = bo;
#pragma unroll
    for (int c = 0; c < 64; ++c) {
      float4 t0 = *(const float4*)&bw[(c * 8) ^ (c & 12)];
      float4 t1 = *(const float4*)&bw[(c * 8 + 4) ^ (c & 12)];
      float wo_ = Wo[c * 64 + lane];
      FMA8(z, wo_)
    }
    __asm__ volatile("" ::: "memory");
    // residual + LayerNorm
    float* tp = T + pbase;
#pragma unroll
    for (int m = 0; m < 8; ++m) {
      float r = tok[m] + z[m];
      float mean = wsum64b(r) * (1.f / 64.f);
      float d = r - mean;
      float var = wsum64b(d * d) * (1.f / 64.f);
      float rstd = rsqrtf(var + 1e-5f);
      tp[m * 64] = d * rstd * gl + bl;
    }
  }
}

// ---- depthwise 3x3 (SAME, zero pad) + GN1 stats — float4 over channels -----
__global__ __launch_bounds__(256) void k_dw(const float* __restrict__ T, float* __restrict__ Y,
                                            const float* __restrict__ dww,
                                            float* __restrict__ stats) {
  __shared__ float red_s[256], red_ss[256];
  int tid = threadIdx.x;
  int b = blockIdx.x >> 5, r = blockIdx.x & 31;   // one row per block
  int half = tid >> 7;                            // cols 0-15 / 16-31
  int mc4 = tid & 127;
  int m = mc4 >> 4, c4 = mc4 & 15, c0 = c4 * 4;
  float4 w9[9];
#pragma unroll
  for (int t = 0; t < 9; ++t) {
    w9[t].x = dww[(c0 + 0) * 9 + t];
    w9[t].y = dww[(c0 + 1) * 9 + t];
    w9[t].z = dww[(c0 + 2) * 9 + t];
    w9[t].w = dww[(c0 + 3) * 9 + t];
  }
  float s = 0.f, ss = 0.f;
  const size_t plane = (size_t)b * 524288 + (size_t)m * 64 + c0;  // + n*512
  for (int ci = 0; ci < 16; ++ci) {
    int col = half * 16 + ci;
    float4 acc = make_float4(0.f, 0.f, 0.f, 0.f);
#pragma unroll
    for (int dh = -1; dh <= 1; ++dh) {
      int rr = r + dh;
      if (rr < 0 || rr > 31) continue;
#pragma unroll
      for (int dx = -1; dx <= 1; ++dx) {
        int cc = col + dx;
        if (cc < 0 || cc > 31) continue;
        float4 tv = *(const float4*)&T[plane + (size_t)(rr * 32 + cc) * 512];
        float4 w = w9[(dh + 1) * 3 + dx + 1];
        acc.x += tv.x * w.x; acc.y += tv.y * w.y;
        acc.z += tv.z * w.z; acc.w += tv.w * w.w;
      }
    }
    *(float4*)&Y[plane + (size_t)(r * 32 + col) * 512] = acc;
    s += acc.x + acc.y + acc.z + acc.w;
    ss += acc.x * acc.x + acc.y * acc.y + acc.z * acc.z + acc.w * acc.w;
  }
  red_s[tid] = s;
  red_ss[tid] = ss;
  __syncthreads();
  if (tid < 64) {  // (m,g): 8 m x 8 groups
    int mm = tid >> 3, g = tid & 7;
    float a = 0.f, a2 = 0.f;
#pragma unroll
    for (int hh = 0; hh < 2; ++hh)
#pragma unroll
      for (int e = 0; e < 2; ++e) {
        int idx = hh * 128 + mm * 16 + g * 2 + e;
        a += red_s[idx];
        a2 += red_ss[idx];
      }
    atomicAdd(&stats[((b * 8 + mm) * 8 + g) * 2 + 0], a);
    atomicAdd(&stats[((b * 8 + mm) * 8 + g) * 2 + 1], a2);
  }
}

// ---- GN1-apply + SiLU + pw conv1x1 (in place on Y) + GN2 stats -------------
__global__ __launch_bounds__(256) void k_pw(float* __restrict__ Y, const float* __restrict__ pw,
                                            const float* __restrict__ g1,
                                            const float* __restrict__ b1,
                                            const float* __restrict__ s1,
                                            float* __restrict__ s2) {
  __shared__ float PWT[4096];
  __shared__ float HB[4][256];
  __shared__ float red_s[256], red_ss[256];
  int tid = threadIdx.x, lane = tid & 63, wv = tid >> 6;
  int bm = blockIdx.x >> 2, pt = blockIdx.x & 3;
  int b = bm >> 3, m = bm & 7;
  int n0 = pt * 256;
  for (int i = tid; i < 4096; i += 256) {
    int o = i >> 6, c = i & 63;
    PWT[c * 64 + o] = pw[i];
  }
  int g = lane >> 3;
  float sg = s1[(bm * 8 + g) * 2], sg2 = s1[(bm * 8 + g) * 2 + 1];
  float mean = sg * (1.f / 8192.f);
  float var = sg2 * (1.f / 8192.f) - mean * mean;
  float rstd = rsqrtf(var + 1e-5f);
  float A = rstd * g1[lane];
  float Bc = b1[lane] - mean * A;
  __syncthreads();
  float st = 0.f, st2 = 0.f;
  const size_t base = (size_t)b * 1024 * 512 + (size_t)m * 64 + lane;
  for (int it = 0; it < 16; ++it) {
    int n = n0 + it * 16 + wv * 4;
    float h[4];
#pragma unroll
    for (int jj = 0; jj < 4; ++jj) {
      float y = Y[base + (size_t)(n + jj) * 512];
      h[jj] = silu_f(y * A + Bc);
    }
    *(float4*)&HB[wv][lane * 4] = make_float4(h[0], h[1], h[2], h[3]);
    __asm__ volatile("" ::: "memory");
    float a0 = 0.f, a1 = 0.f, a2 = 0.f, a3 = 0.f;
#pragma unroll 8
    for (int c = 0; c < 64; ++c) {
      float4 hh = *(const float4*)&HB[wv][c * 4];
      float w = PWT[c * 64 + lane];
      a0 += hh.x * w; a1 += hh.y * w; a2 += hh.z * w; a3 += hh.w * w;
    }
    float vals[4] = {a0, a1, a2, a3};
#pragma unroll
    for (int jj = 0; jj < 4; ++jj) {
      Y[base + (size_t)(n + jj) * 512] = vals[jj];
      st += vals[jj];
      st2 += vals[jj] * vals[jj];
    }
    __asm__ volatile("" ::: "memory");
  }
  red_s[tid] = st;
  red_ss[tid] = st2;
  __syncthreads();
  if (tid < 8) {
    float a = 0.f, a2 = 0.f;
    for (int w4 = 0; w4 < 4; ++w4)
      for (int j = 0; j < 8; ++j) {
        int t2 = w4 * 64 + tid * 8 + j;
        a += red_s[t2]; a2 += red_ss[t2];
      }
    atomicAdd(&s2[(bm * 8 + tid) * 2 + 0], a);
    atomicAdd(&s2[(bm * 8 + tid) * 2 + 1], a2);
  }
}

// ---- GN2-apply + residual + SiLU + present mask -> X (final layer only) ----
__global__ __launch_bounds__(256) void k_fuse(const float* __restrict__ T,
                                              const float* __restrict__ Y,
                                              float* __restrict__ X,
                                              const float* __restrict__ g2,
                                              const float* __restrict__ b2,
                                              const float* __restrict__ s2,
                                              const float* __restrict__ present) {
  int tid = threadIdx.x, lane = tid & 63, wv = tid >> 6;
  int bm = blockIdx.x >> 3, pt = blockIdx.x & 7;
  int b = bm >> 3, m = bm & 7;
  int g = lane >> 3;
  float sg = s2[(bm * 8 + g) * 2], sg2 = s2[(bm * 8 + g) * 2 + 1];
  float mean = sg * (1.f / 8192.f);
  float var = sg2 * (1.f / 8192.f) - mean * mean;
  float rstd = rsqrtf(var + 1e-5f);
  float A = rstd * g2[lane];
  float Bc = b2[lane] - mean * A;
  float pres = present[bm];
  const size_t base = (size_t)b * 1024 * 512 + (size_t)m * 64 + lane;
  int n0 = pt * 128;
  for (int i2 = 0; i2 < 32; ++i2) {
    int n = n0 + i2 * 4 + wv;
    size_t idx = base + (size_t)n * 512;
    float z = T[idx] + (Y[idx] * A + Bc);
    X[idx] = silu_f(z) * pres;
  }
}

// ---- heads: policy logits + opp_move ---------------------------------------
__global__ __launch_bounds__(256) void k_heads_px(const float* __restrict__ X,
                                                  const float* __restrict__ pol_w,
                                                  const float* __restrict__ pol_b,
                                                  const float* __restrict__ om_w,
                                                  const float* __restrict__ om_b,
                                                  const float* __restrict__ present,
                                                  float* __restrict__ out) {
  int tid = threadIdx.x, lane = tid & 63, wv = tid >> 6;
  int b = blockIdx.x >> 4, n0 = (blockIdx.x & 15) * 64;
  float pw_ = pol_w[lane];
  for (int it = 0; it < 16; ++it) {
    int n = n0 + wv * 16 + it;
    const float* xp = X + ((size_t)(b * 1024 + n) * 8) * 64 + lane;
#pragma unroll
    for (int m = 0; m < 8; ++m) {
      float v = xp[m * 64];
      float d = wsum64(v * om_w[m * 64 + lane]);
      if (m == 0) {
        float dp = wsum64(v * pw_);
        if (lane == 0) out[b * 1024 + n] = dp + pol_b[0];
      }
      if (lane == 0)
        out[16400u + (size_t)(b * 8 + m) * 1024 + n] = (d + om_b[m]) * present[b * 8 + m];
    }
  }
}

// ---- heads: spatial mean pool ----------------------------------------------
__global__ __launch_bounds__(256) void k_pool(const float* __restrict__ X,
                                              float* __restrict__ pooled) {
  __shared__ float red[256];
  int tid = threadIdx.x, lane = tid & 63, wv = tid >> 6;
  int b = blockIdx.x >> 3, m = blockIdx.x & 7;
  float s = 0.f;
  for (int p = wv; p < 1024; p += 4)
    s += X[((size_t)(b * 1024 + p) * 8 + m) * 64 + lane];
  red[tid] = s;
  __syncthreads();
  if (tid < 64)
    pooled[(b * 8 + m) * 64 + tid] =
        (red[tid] + red[tid + 64] + red[tid + 128] + red[tid + 192]) * (1.f / 1024.f);
}

// ---- heads: value MLP + opp_param MLP --------------------------------------
__global__ __launch_bounds__(64) void k_heads_vec(
    const float* __restrict__ pooled, const float* __restrict__ vh_w1,
    const float* __restrict__ vh_b1, const float* __restrict__ vh_w2,
    const float* __restrict__ vh_b2, const float* __restrict__ op_w1,
    const float* __restrict__ op_b1, const float* __restrict__ op_w2,
    const float* __restrict__ op_b2, const float* __restrict__ present,
    float* __restrict__ out) {
  int lane = threadIdx.x;
  int b = blockIdx.x >> 3, m = blockIdx.x & 7;
  const float* pp = pooled + (b * 8 + m) * 64;
  float h = op_b1[lane];
  for (int c = 0; c < 64; ++c) h += pp[c] * op_w1[lane * 64 + c];
  h = silu_f(h);
  float pres = present[b * 8 + m];
  for (int jj = 0; jj < 5; ++jj) {
    float d = wsum64(h * op_w2[(m * 5 + jj) * 64 + lane]);
    if (lane == 0) out[147472u + (b * 8 + m) * 5 + jj] = (d + op_b2[m * 5 + jj]) * pres;
  }
  if (m == 0) {
    float hv = vh_b1[lane];
    for (int c = 0; c < 64; ++c) hv += pp[c] * vh_w1[lane * 64 + c];
    hv = silu_f(hv);
    float dv = wsum64(hv * vh_w2[lane]);
    if (lane == 0) out[16384u + b] = dv + vh_b2[0];
  }
}

// ---------------------------------------------------------------------------
extern "C" void kernel_launch(void* const* d_in, const int* in_sizes, int n_in,
                              void* d_out, int out_size, void* d_ws, size_t ws_size,
                              hipStream_t stream) {
  const float* board  = (const float*)d_in[0];
  const float* stem_w = (const float*)d_in[1];
  const float* stem_g = (const float*)d_in[2];
  const float* stem_b = (const float*)d_in[3];
  const float* qw = (const float*)d_in[4];
  const float* qb = (const float*)d_in[5];
  const float* kw = (const float*)d_in[6];
  const float* kb = (const float*)d_in[7];
  const float* vw = (const float*)d_in[8];
  const float* vb = (const float*)d_in[9];
  const float* ow = (const float*)d_in[10];
  const float* ob = (const float*)d_in[11];
  const float* ln_g = (const float*)d_in[12];
  const float* ln_b = (const float*)d_in[13];
  const float* dw_w = (const float*)d_in[14];
  const float* gn1_g = (const float*)d_in[15];
  const float* gn1_b = (const float*)d_in[16];
  const float* pw_w = (const float*)d_in[17];
  const float* gn2_g = (const float*)d_in[18];
  const float* gn2_b = (const float*)d_in[19];
  const float* pol_w = (const float*)d_in[20];
  const float* pol_b = (const float*)d_in[21];
  const float* vh_w1 = (const float*)d_in[22];
  const float* vh_b1 = (const float*)d_in[23];
  const float* vh_w2 = (const float*)d_in[24];
  const float* vh_b2 = (const float*)d_in[25];
  const float* om_w = (const float*)d_in[26];
  const float* om_b = (const float*)d_in[27];
  const float* op_w1 = (const float*)d_in[28];
  const float* op_b1 = (const float*)d_in[29];
  const float* op_w2 = (const float*)d_in[30];
  const float* op_b2 = (const float*)d_in[31];
  float* ws = (float*)d_ws;
  float* out = (float*)d_out;

  (void)hipFuncSetAttribute((const void*)k_attn,
                            hipFuncAttributeMaxDynamicSharedMemorySize,
                            ATTN_LDS_BYTES);

  k_init<<<64, 256, 0, stream>>>(board, ws);
  k_stem<<<256, 256, 0, stream>>>(board, stem_w, ws);
  k_gn_silu<<<2048, 256, 0, stream>>>(ws + WSX, stem_g, stem_b, ws + WSS);

  for (int i = 0; i < 6; ++i) {
    float* s1 = ws + WSS + (size_t)(1 + 2 * i) * 2048;
    float* s2 = ws + WSS + (size_t)(2 + 2 * i) * 2048;
    if (i == 0) {
      k_attn<<<512, 512, ATTN_LDS_BYTES, stream>>>(
          ws + WSX, ws + WSX, ws + WSS, gn2_g, gn2_b, ws + WST,
          qw, qb, kw, kb, vw, vb, ow, ob, ln_g, ln_b, ws + WSP, 0);
    } else {
      float* s2prev = ws + WSS + (size_t)(2 * i) * 2048;  // layer i-1's GN2 stats
      k_attn<<<512, 512, ATTN_LDS_BYTES, stream>>>(
          ws + WST, ws + WSY, s2prev, gn2_g + (i - 1) * 64, gn2_b + (i - 1) * 64,
          ws + WST, qw + i * 4096, qb + i * 64, kw + i * 4096, kb + i * 64,
          vw + i * 4096, vb + i * 64, ow + i * 4096, ob + i * 64, ln_g + i * 64,
          ln_b + i * 64, ws + WSP, 1);
    }
    k_dw<<<512, 256, 0, stream>>>(ws + WST, ws + WSY, dw_w + i * 576, s1);
    k_pw<<<512, 256, 0, stream>>>(ws + WSY, pw_w + i * 4096, gn1_g + i * 64,
                                  gn1_b + i * 64, s1, s2);
  }
  // final layer epilogue -> X for heads
  k_fuse<<<1024, 256, 0, stream>>>(ws + WST, ws + WSY, ws + WSX, gn2_g + 5 * 64,
                                   gn2_b + 5 * 64, ws + WSS + (size_t)12 * 2048,
                                   ws + WSP);

  k_heads_px<<<256, 256, 0, stream>>>(ws + WSX, pol_w, pol_b, om_w, om_b, ws + WSP, out);
  k_pool<<<128, 256, 0, stream>>>(ws + WSX, ws + WSPL);
  k_heads_vec<<<128, 64, 0, stream>>>(ws + WSPL, vh_w1, vh_b1, vh_w2, vh_b2, op_w1,
                                      op_b1, op_w2, op_b2, ws + WSP, out);
}

// Round 13
// 1265.322 us; speedup vs baseline: 1.4683x; 1.1154x over previous
//
#include <hip/hip_runtime.h>
#include <cstddef>

// ---------------------------------------------------------------------------
// PolicyValueDWPixelPlayerAttnNoFFNNet — fp32, round 12
// Layout: [b][n=h*32+w][m][c], c fastest.
// R12: present-mask-aware work skipping. m_each in 2..8 per batch item;
//      masked players cannot affect outputs (per-(b,m) norms, masked heads).
//      k_attn: template<MB in {4,6,8}>; k_dw: thread skip; k_pw: block skip.
// ---------------------------------------------------------------------------

#define WSX   0u
#define WST   8388608u
#define WSY   16777216u
#define WSS   25165824u
#define WSP   (WSS + 26624u)     // present[128], then m_each[16]
#define WSPL  (WSP + 160u)       // pooled

#define ATTN_LDS_BYTES ((4 * 64 * 64 + 8 * 64 * 8) * 4)  // 64KB W + 16KB BUF

__device__ __forceinline__ float silu_f(float x) { return x / (1.f + __expf(-x)); }

__device__ __forceinline__ float wsum64(float v) {
#pragma unroll
  for (int s = 1; s < 64; s <<= 1) v += __shfl_xor(v, s);
  return v;
}

// sum within each 16-lane DPP row (VALU, no LDS): ror 8,4,2,1
__device__ __forceinline__ float rowsum16(float v) {
  v += __int_as_float(__builtin_amdgcn_update_dpp(0, __float_as_int(v), 0x128, 0xf, 0xf, true));
  v += __int_as_float(__builtin_amdgcn_update_dpp(0, __float_as_int(v), 0x124, 0xf, 0xf, true));
  v += __int_as_float(__builtin_amdgcn_update_dpp(0, __float_as_int(v), 0x122, 0xf, 0xf, true));
  v += __int_as_float(__builtin_amdgcn_update_dpp(0, __float_as_int(v), 0x121, 0xf, 0xf, true));
  return v;
}

// full 64-lane sum: DPP within rows, shfl across rows (2 LDS ops)
__device__ __forceinline__ float wsum64b(float v) {
  v = rowsum16(v);
  v += __shfl_xor(v, 16);
  v += __shfl_xor(v, 32);
  return v;
}

// ---- init: zero stats, compute present mask + m_each -----------------------
__global__ __launch_bounds__(256) void k_init(const float* __restrict__ board,
                                              float* __restrict__ ws) {
  int tid = threadIdx.x;
  for (unsigned i = blockIdx.x * 256 + tid; i < 26624u; i += 64u * 256u) ws[WSS + i] = 0.f;
  if (blockIdx.x == 0 && tid < 128) {
    int b = tid >> 3, m = tid & 7;
    float best = board[(size_t)(b * 149 + 7) * 1024];
    int bi = 0;
    for (int ch = 1; ch < 7; ++ch) {
      float v = board[(size_t)(b * 149 + 7 + ch) * 1024];
      if (v > best) { best = v; bi = ch; }
    }
    int m_each = bi + 2;  // 2..8
    ws[WSP + tid] = (m < m_each) ? 1.f : 0.f;
    if (m == 0) ws[WSP + 128 + b] = (float)m_each;
  }
}

// ---- stem: conv1x1 (35->64) into X + GN stats ------------------------------
__global__ __launch_bounds__(256) void k_stem(const float* __restrict__ board,
                                              const float* __restrict__ stem_w,
                                              float* __restrict__ ws) {
  __shared__ float A[147 * 64];   // [ch][pix]
  __shared__ float WT[35 * 64];   // [c][o]
  __shared__ float red_s[256], red_ss[256];
  int tid = threadIdx.x;
  int b = blockIdx.x >> 4, n0 = (blockIdx.x & 15) * 64;
  for (int i = tid; i < 147 * 64; i += 256) {
    int c = i >> 6, p = i & 63;
    A[i] = board[(size_t)(b * 149 + c) * 1024 + n0 + p];
  }
  for (int i = tid; i < 35 * 64; i += 256) {
    int o = i / 35, c = i % 35;
    WT[c * 64 + o] = stem_w[i];
  }
  __syncthreads();
  int o = tid & 63, wv = tid >> 6;
  float* X = ws + WSX;
  float st_s[8], st_ss[8];
#pragma unroll
  for (int m = 0; m < 8; ++m) { st_s[m] = 0.f; st_ss[m] = 0.f; }
  for (int m = 0; m < 8; ++m) {
    for (int k = 0; k < 4; ++k) {
      int q = wv + 4 * k;
      float a0 = 0.f, a1 = 0.f, a2 = 0.f, a3 = 0.f;
#pragma unroll
      for (int c = 0; c < 19; ++c) {
        float w = WT[c * 64 + o];
        float4 av = *(const float4*)&A[c * 64 + q * 4];
        a0 += av.x * w; a1 += av.y * w; a2 += av.z * w; a3 += av.w * w;
      }
#pragma unroll
      for (int j = 0; j < 16; ++j) {
        float w = WT[(19 + j) * 64 + o];
        float4 av = *(const float4*)&A[(19 + m * 16 + j) * 64 + q * 4];
        a0 += av.x * w; a1 += av.y * w; a2 += av.z * w; a3 += av.w * w;
      }
      int n = n0 + q * 4;
      float vals[4] = {a0, a1, a2, a3};
#pragma unroll
      for (int j = 0; j < 4; ++j) {
        X[((size_t)(b * 1024 + n + j) * 8 + m) * 64 + o] = vals[j];
        st_s[m] += vals[j];
        st_ss[m] += vals[j] * vals[j];
      }
    }
  }
  float* stats = ws + WSS;
  for (int m = 0; m < 8; ++m) {
    __syncthreads();
    red_s[tid] = st_s[m];
    red_ss[tid] = st_ss[m];
    __syncthreads();
    if (tid < 8) {
      float a = 0.f, a2 = 0.f;
      for (int w4 = 0; w4 < 4; ++w4)
        for (int j = 0; j < 8; ++j) {
          int t2 = w4 * 64 + tid * 8 + j;
          a += red_s[t2]; a2 += red_ss[t2];
        }
      atomicAdd(&stats[((b * 8 + m) * 8 + tid) * 2 + 0], a);
      atomicAdd(&stats[((b * 8 + m) * 8 + tid) * 2 + 1], a2);
    }
  }
}

// ---- apply GN (+weights) + SiLU in place on X (stem only) ------------------
__global__ __launch_bounds__(256) void k_gn_silu(float* __restrict__ X,
                                                 const float* __restrict__ g,
                                                 const float* __restrict__ bt,
                                                 const float* __restrict__ stats) {
  for (size_t idx = (size_t)blockIdx.x * 256 + threadIdx.x; idx < 8388608ull;
       idx += (size_t)2048 * 256) {
    int c = (int)(idx & 63);
    int m = (int)((idx >> 6) & 7);
    int b = (int)(idx >> 19);
    int gi = ((b * 8 + m) * 8 + (c >> 3)) * 2;
    float s = stats[gi], s2 = stats[gi + 1];
    float mean = s * (1.f / 8192.f);
    float var = s2 * (1.f / 8192.f) - mean * mean;
    float rstd = rsqrtf(var + 1e-5f);
    float v = (X[idx] - mean) * rstd * g[c] + bt[c];
    X[idx] = silu_f(v);
  }
}

// ---- fused per-pixel attention + residual + LayerNorm ----------------------
template <int MB>
__device__ __forceinline__ void attn_core(
    const float* __restrict__ Xin, const float* __restrict__ Yin,
    float* __restrict__ T, const float* Wq, const float* Wk, const float* Wv,
    const float* Wo, float* bw, int b, int n0, int wv, int lane, int sw,
    float bq, float bk, float bv, float bo, float gl, float bl,
    unsigned pmask, const float* Ag, const float* Bg, int fused) {
  for (int j = 0; j < 4; ++j) {
    int n = n0 + wv * 4 + j;
    size_t pbase = ((size_t)(b * 1024 + n) * 8) * 64 + lane;
    float tok[8] = {0.f, 0.f, 0.f, 0.f, 0.f, 0.f, 0.f, 0.f};
    if (fused) {
#pragma unroll
      for (int m = 0; m < MB; ++m) {
        float tv = Xin[pbase + m * 64];
        float yv = Yin[pbase + m * 64];
        float z = tv + (yv * Ag[m] + Bg[m]);
        float pres = ((pmask >> m) & 1) ? 1.f : 0.f;
        tok[m] = silu_f(z) * pres;
      }
    } else {
#pragma unroll
      for (int m = 0; m < MB; ++m) tok[m] = Xin[pbase + m * 64];
    }
    *(float4*)&bw[(lane * 8) ^ sw]     = make_float4(tok[0], tok[1], tok[2], tok[3]);
    *(float4*)&bw[(lane * 8 + 4) ^ sw] = make_float4(tok[4], tok[5], tok[6], tok[7]);
    __asm__ volatile("" ::: "memory");
    float aq[MB], ak[MB], av[MB];
#pragma unroll
    for (int m = 0; m < MB; ++m) { aq[m] = bq; ak[m] = bk; av[m] = bv; }
#pragma unroll
    for (int c = 0; c < 64; ++c) {
      float4 t0 = *(const float4*)&bw[(c * 8) ^ (c & 12)];
      float4 t1 = *(const float4*)&bw[(c * 8 + 4) ^ (c & 12)];
      float tarr[8] = {t0.x, t0.y, t0.z, t0.w, t1.x, t1.y, t1.z, t1.w};
      float wq_ = Wq[c * 64 + lane];
      float wk_ = Wk[c * 64 + lane];
      float wv_ = Wv[c * 64 + lane];
#pragma unroll
      for (int m = 0; m < MB; ++m) {
        aq[m] = fmaf(tarr[m], wq_, aq[m]);
        ak[m] = fmaf(tarr[m], wk_, ak[m]);
        av[m] = fmaf(tarr[m], wv_, av[m]);
      }
    }
    float ao[8] = {0.f, 0.f, 0.f, 0.f, 0.f, 0.f, 0.f, 0.f};
#pragma unroll
    for (int mq = 0; mq < MB; ++mq) {
      float lg[MB];
#pragma unroll
      for (int mk = 0; mk < MB; ++mk)
        lg[mk] = rowsum16(aq[mq] * ak[mk]) * 0.25f;
      float mx = -3.0e38f;
#pragma unroll
      for (int mk = 0; mk < MB; ++mk)
        if ((pmask >> mk) & 1) mx = fmaxf(mx, lg[mk]);
      float se = 0.f, acc = 0.f;
#pragma unroll
      for (int mk = 0; mk < MB; ++mk) {
        float e = ((pmask >> mk) & 1) ? __expf(lg[mk] - mx) : 0.f;
        se += e;
        acc += e * av[mk];
      }
      ao[mq] = acc * __builtin_amdgcn_rcpf(se);
    }
    __asm__ volatile("" ::: "memory");
    *(float4*)&bw[(lane * 8) ^ sw]     = make_float4(ao[0], ao[1], ao[2], ao[3]);
    *(float4*)&bw[(lane * 8 + 4) ^ sw] = make_float4(ao[4], ao[5], ao[6], ao[7]);
    __asm__ volatile("" ::: "memory");
    float z[MB];
#pragma unroll
    for (int m = 0; m < MB; ++m) z[m] = bo;
#pragma unroll
    for (int c = 0; c < 64; ++c) {
      float4 t0 = *(const float4*)&bw[(c * 8) ^ (c & 12)];
      float4 t1 = *(const float4*)&bw[(c * 8 + 4) ^ (c & 12)];
      float tarr[8] = {t0.x, t0.y, t0.z, t0.w, t1.x, t1.y, t1.z, t1.w};
      float wo_ = Wo[c * 64 + lane];
#pragma unroll
      for (int m = 0; m < MB; ++m) z[m] = fmaf(tarr[m], wo_, z[m]);
    }
    __asm__ volatile("" ::: "memory");
    float* tp = T + pbase;
#pragma unroll
    for (int m = 0; m < MB; ++m) {
      float r = tok[m] + z[m];
      float mean = wsum64b(r) * (1.f / 64.f);
      float d = r - mean;
      float var = wsum64b(d * d) * (1.f / 64.f);
      float rstd = rsqrtf(var + 1e-5f);
      tp[m * 64] = d * rstd * gl + bl;
    }
  }
}

__global__ __launch_bounds__(512, 4) void k_attn(
    const float* __restrict__ Xin, const float* __restrict__ Yin,
    const float* __restrict__ s2p, const float* __restrict__ g2p,
    const float* __restrict__ b2p, float* __restrict__ T,
    const float* __restrict__ qw, const float* __restrict__ qb,
    const float* __restrict__ kw, const float* __restrict__ kb,
    const float* __restrict__ vw, const float* __restrict__ vb,
    const float* __restrict__ ow, const float* __restrict__ ob,
    const float* __restrict__ lng, const float* __restrict__ lnb,
    const float* __restrict__ present, int fused) {
  extern __shared__ float sm[];
  float* Wq = sm;
  float* Wk = sm + 4096;
  float* Wv = sm + 8192;
  float* Wo = sm + 12288;
  float* BUF = sm + 16384;
  int tid = threadIdx.x;
  int lane = tid & 63, wv = tid >> 6;
  int b = blockIdx.x >> 5;
  int n0 = (blockIdx.x & 31) * 32;
  for (int i = tid; i < 4096; i += 512) {
    int o = i >> 6, c = i & 63;
    Wq[c * 64 + o] = qw[i];
    Wk[c * 64 + o] = kw[i];
    Wv[c * 64 + o] = vw[i];
    Wo[c * 64 + o] = ow[i];
  }
  float bq = qb[lane], bk = kb[lane], bv = vb[lane], bo = ob[lane];
  float gl = lng[lane], bl = lnb[lane];
  unsigned pmask = 0;
#pragma unroll
  for (int m = 0; m < 8; ++m) pmask |= (present[b * 8 + m] > 0.5f) ? (1u << m) : 0u;
  int mea = (int)present[128 + b];
  float Ag[8], Bg[8];
  if (fused) {
    int g = lane >> 3;
    float gw = g2p[lane], bw_ = b2p[lane];
#pragma unroll
    for (int m = 0; m < 8; ++m) {
      int gi = ((b * 8 + m) * 8 + g) * 2;
      float sg = s2p[gi], sg2 = s2p[gi + 1];
      float mean = sg * (1.f / 8192.f);
      float var = sg2 * (1.f / 8192.f) - mean * mean;
      float rstd = rsqrtf(var + 1e-5f);
      Ag[m] = rstd * gw;
      Bg[m] = bw_ - mean * Ag[m];
    }
  }
  __syncthreads();
  float* bw = BUF + wv * 512;
  const int sw = lane & 12;
  if (mea <= 4)
    attn_core<4>(Xin, Yin, T, Wq, Wk, Wv, Wo, bw, b, n0, wv, lane, sw,
                 bq, bk, bv, bo, gl, bl, pmask, Ag, Bg, fused);
  else if (mea <= 6)
    attn_core<6>(Xin, Yin, T, Wq, Wk, Wv, Wo, bw, b, n0, wv, lane, sw,
                 bq, bk, bv, bo, gl, bl, pmask, Ag, Bg, fused);
  else
    attn_core<8>(Xin, Yin, T, Wq, Wk, Wv, Wo, bw, b, n0, wv, lane, sw,
                 bq, bk, bv, bo, gl, bl, pmask, Ag, Bg, fused);
}

// ---- depthwise 3x3 (SAME, zero pad) + GN1 stats — float4 over channels -----
__global__ __launch_bounds__(256) void k_dw(const float* __restrict__ T, float* __restrict__ Y,
                                            const float* __restrict__ dww,
                                            float* __restrict__ stats,
                                            const float* __restrict__ present) {
  __shared__ float red_s[256], red_ss[256];
  int tid = threadIdx.x;
  int b = blockIdx.x >> 5, r = blockIdx.x & 31;
  int half = tid >> 7;
  int mc4 = tid & 127;
  int m = mc4 >> 4, c4 = mc4 & 15, c0 = c4 * 4;
  int mea = (int)present[128 + b];
  float s = 0.f, ss = 0.f;
  if (m < mea) {
    float4 w9[9];
#pragma unroll
    for (int t = 0; t < 9; ++t) {
      w9[t].x = dww[(c0 + 0) * 9 + t];
      w9[t].y = dww[(c0 + 1) * 9 + t];
      w9[t].z = dww[(c0 + 2) * 9 + t];
      w9[t].w = dww[(c0 + 3) * 9 + t];
    }
    const size_t plane = (size_t)b * 524288 + (size_t)m * 64 + c0;
    for (int ci = 0; ci < 16; ++ci) {
      int col = half * 16 + ci;
      float4 acc = make_float4(0.f, 0.f, 0.f, 0.f);
#pragma unroll
      for (int dh = -1; dh <= 1; ++dh) {
        int rr = r + dh;
        if (rr < 0 || rr > 31) continue;
#pragma unroll
        for (int dx = -1; dx <= 1; ++dx) {
          int cc = col + dx;
          if (cc < 0 || cc > 31) continue;
          float4 tv = *(const float4*)&T[plane + (size_t)(rr * 32 + cc) * 512];
          float4 w = w9[(dh + 1) * 3 + dx + 1];
          acc.x += tv.x * w.x; acc.y += tv.y * w.y;
          acc.z += tv.z * w.z; acc.w += tv.w * w.w;
        }
      }
      *(float4*)&Y[plane + (size_t)(r * 32 + col) * 512] = acc;
      s += acc.x + acc.y + acc.z + acc.w;
      ss += acc.x * acc.x + acc.y * acc.y + acc.z * acc.z + acc.w * acc.w;
    }
  }
  red_s[tid] = s;
  red_ss[tid] = ss;
  __syncthreads();
  if (tid < 64) {
    int mm = tid >> 3, g = tid & 7;
    float a = 0.f, a2 = 0.f;
#pragma unroll
    for (int hh = 0; hh < 2; ++hh)
#pragma unroll
      for (int e = 0; e < 2; ++e) {
        int idx = hh * 128 + mm * 16 + g * 2 + e;
        a += red_s[idx];
        a2 += red_ss[idx];
      }
    atomicAdd(&stats[((b * 8 + mm) * 8 + g) * 2 + 0], a);
    atomicAdd(&stats[((b * 8 + mm) * 8 + g) * 2 + 1], a2);
  }
}

// ---- GN1-apply + SiLU + pw conv1x1 (in place on Y) + GN2 stats -------------
__global__ __launch_bounds__(256) void k_pw(float* __restrict__ Y, const float* __restrict__ pw,
                                            const float* __restrict__ g1,
                                            const float* __restrict__ b1,
                                            const float* __restrict__ s1,
                                            float* __restrict__ s2,
                                            const float* __restrict__ present) {
  __shared__ float PWT[4096];
  __shared__ float HB[4][256];
  __shared__ float red_s[256], red_ss[256];
  int tid = threadIdx.x, lane = tid & 63, wv = tid >> 6;
  int bm = blockIdx.x >> 2, pt = blockIdx.x & 3;
  int b = bm >> 3, m = bm & 7;
  if (m >= (int)present[128 + b]) return;  // absent player: outputs unused
  int n0 = pt * 256;
  for (int i = tid; i < 4096; i += 256) {
    int o = i >> 6, c = i & 63;
    PWT[c * 64 + o] = pw[i];
  }
  int g = lane >> 3;
  float sg = s1[(bm * 8 + g) * 2], sg2 = s1[(bm * 8 + g) * 2 + 1];
  float mean = sg * (1.f / 8192.f);
  float var = sg2 * (1.f / 8192.f) - mean * mean;
  float rstd = rsqrtf(var + 1e-5f);
  float A = rstd * g1[lane];
  float Bc = b1[lane] - mean * A;
  __syncthreads();
  float st = 0.f, st2 = 0.f;
  const size_t base = (size_t)b * 1024 * 512 + (size_t)m * 64 + lane;
  for (int it = 0; it < 16; ++it) {
    int n = n0 + it * 16 + wv * 4;
    float h[4];
#pragma unroll
    for (int jj = 0; jj < 4; ++jj) {
      float y = Y[base + (size_t)(n + jj) * 512];
      h[jj] = silu_f(y * A + Bc);
    }
    *(float4*)&HB[wv][lane * 4] = make_float4(h[0], h[1], h[2], h[3]);
    __asm__ volatile("" ::: "memory");
    float a0 = 0.f, a1 = 0.f, a2 = 0.f, a3 = 0.f;
#pragma unroll 8
    for (int c = 0; c < 64; ++c) {
      float4 hh = *(const float4*)&HB[wv][c * 4];
      float w = PWT[c * 64 + lane];
      a0 += hh.x * w; a1 += hh.y * w; a2 += hh.z * w; a3 += hh.w * w;
    }
    float vals[4] = {a0, a1, a2, a3};
#pragma unroll
    for (int jj = 0; jj < 4; ++jj) {
      Y[base + (size_t)(n + jj) * 512] = vals[jj];
      st += vals[jj];
      st2 += vals[jj] * vals[jj];
    }
    __asm__ volatile("" ::: "memory");
  }
  red_s[tid] = st;
  red_ss[tid] = st2;
  __syncthreads();
  if (tid < 8) {
    float a = 0.f, a2 = 0.f;
    for (int w4 = 0; w4 < 4; ++w4)
      for (int j = 0; j < 8; ++j) {
        int t2 = w4 * 64 + tid * 8 + j;
        a += red_s[t2]; a2 += red_ss[t2];
      }
    atomicAdd(&s2[(bm * 8 + tid) * 2 + 0], a);
    atomicAdd(&s2[(bm * 8 + tid) * 2 + 1], a2);
  }
}

// ---- GN2-apply + residual + SiLU + present mask -> X (final layer only) ----
__global__ __launch_bounds__(256) void k_fuse(const float* __restrict__ T,
                                              const float* __restrict__ Y,
                                              float* __restrict__ X,
                                              const float* __restrict__ g2,
                                              const float* __restrict__ b2,
                                              const float* __restrict__ s2,
                                              const float* __restrict__ present) {
  int tid = threadIdx.x, lane = tid & 63, wv = tid >> 6;
  int bm = blockIdx.x >> 3, pt = blockIdx.x & 7;
  int b = bm >> 3, m = bm & 7;
  int g = lane >> 3;
  float sg = s2[(bm * 8 + g) * 2], sg2 = s2[(bm * 8 + g) * 2 + 1];
  float mean = sg * (1.f / 8192.f);
  float var = sg2 * (1.f / 8192.f) - mean * mean;
  float rstd = rsqrtf(var + 1e-5f);
  float A = rstd * g2[lane];
  float Bc = b2[lane] - mean * A;
  float pres = present[bm];
  const size_t base = (size_t)b * 1024 * 512 + (size_t)m * 64 + lane;
  int n0 = pt * 128;
  for (int i2 = 0; i2 < 32; ++i2) {
    int n = n0 + i2 * 4 + wv;
    size_t idx = base + (size_t)n * 512;
    float z = T[idx] + (Y[idx] * A + Bc);
    X[idx] = silu_f(z) * pres;
  }
}

// ---- heads: policy logits + opp_move ---------------------------------------
__global__ __launch_bounds__(256) void k_heads_px(const float* __restrict__ X,
                                                  const float* __restrict__ pol_w,
                                                  const float* __restrict__ pol_b,
                                                  const float* __restrict__ om_w,
                                                  const float* __restrict__ om_b,
                                                  const float* __restrict__ present,
                                                  float* __restrict__ out) {
  int tid = threadIdx.x, lane = tid & 63, wv = tid >> 6;
  int b = blockIdx.x >> 4, n0 = (blockIdx.x & 15) * 64;
  float pw_ = pol_w[lane];
  for (int it = 0; it < 16; ++it) {
    int n = n0 + wv * 16 + it;
    const float* xp = X + ((size_t)(b * 1024 + n) * 8) * 64 + lane;
#pragma unroll
    for (int m = 0; m < 8; ++m) {
      float v = xp[m * 64];
      float d = wsum64(v * om_w[m * 64 + lane]);
      if (m == 0) {
        float dp = wsum64(v * pw_);
        if (lane == 0) out[b * 1024 + n] = dp + pol_b[0];
      }
      if (lane == 0)
        out[16400u + (size_t)(b * 8 + m) * 1024 + n] = (d + om_b[m]) * present[b * 8 + m];
    }
  }
}

// ---- heads: spatial mean pool ----------------------------------------------
__global__ __launch_bounds__(256) void k_pool(const float* __restrict__ X,
                                              float* __restrict__ pooled) {
  __shared__ float red[256];
  int tid = threadIdx.x, lane = tid & 63, wv = tid >> 6;
  int b = blockIdx.x >> 3, m = blockIdx.x & 7;
  float s = 0.f;
  for (int p = wv; p < 1024; p += 4)
    s += X[((size_t)(b * 1024 + p) * 8 + m) * 64 + lane];
  red[tid] = s;
  __syncthreads();
  if (tid < 64)
    pooled[(b * 8 + m) * 64 + tid] =
        (red[tid] + red[tid + 64] + red[tid + 128] + red[tid + 192]) * (1.f / 1024.f);
}

// ---- heads: value MLP + opp_param MLP --------------------------------------
__global__ __launch_bounds__(64) void k_heads_vec(
    const float* __restrict__ pooled, const float* __restrict__ vh_w1,
    const float* __restrict__ vh_b1, const float* __restrict__ vh_w2,
    const float* __restrict__ vh_b2, const float* __restrict__ op_w1,
    const float* __restrict__ op_b1, const float* __restrict__ op_w2,
    const float* __restrict__ op_b2, const float* __restrict__ present,
    float* __restrict__ out) {
  int lane = threadIdx.x;
  int b = blockIdx.x >> 3, m = blockIdx.x & 7;
  const float* pp = pooled + (b * 8 + m) * 64;
  float h = op_b1[lane];
  for (int c = 0; c < 64; ++c) h += pp[c] * op_w1[lane * 64 + c];
  h = silu_f(h);
  float pres = present[b * 8 + m];
  for (int jj = 0; jj < 5; ++jj) {
    float d = wsum64(h * op_w2[(m * 5 + jj) * 64 + lane]);
    if (lane == 0) out[147472u + (b * 8 + m) * 5 + jj] = (d + op_b2[m * 5 + jj]) * pres;
  }
  if (m == 0) {
    float hv = vh_b1[lane];
    for (int c = 0; c < 64; ++c) hv += pp[c] * vh_w1[lane * 64 + c];
    hv = silu_f(hv);
    float dv = wsum64(hv * vh_w2[lane]);
    if (lane == 0) out[16384u + b] = dv + vh_b2[0];
  }
}

// ---------------------------------------------------------------------------
extern "C" void kernel_launch(void* const* d_in, const int* in_sizes, int n_in,
                              void* d_out, int out_size, void* d_ws, size_t ws_size,
                              hipStream_t stream) {
  const float* board  = (const float*)d_in[0];
  const float* stem_w = (const float*)d_in[1];
  const float* stem_g = (const float*)d_in[2];
  const float* stem_b = (const float*)d_in[3];
  const float* qw = (const float*)d_in[4];
  const float* qb = (const float*)d_in[5];
  const float* kw = (const float*)d_in[6];
  const float* kb = (const float*)d_in[7];
  const float* vw = (const float*)d_in[8];
  const float* vb = (const float*)d_in[9];
  const float* ow = (const float*)d_in[10];
  const float* ob = (const float*)d_in[11];
  const float* ln_g = (const float*)d_in[12];
  const float* ln_b = (const float*)d_in[13];
  const float* dw_w = (const float*)d_in[14];
  const float* gn1_g = (const float*)d_in[15];
  const float* gn1_b = (const float*)d_in[16];
  const float* pw_w = (const float*)d_in[17];
  const float* gn2_g = (const float*)d_in[18];
  const float* gn2_b = (const float*)d_in[19];
  const float* pol_w = (const float*)d_in[20];
  const float* pol_b = (const float*)d_in[21];
  const float* vh_w1 = (const float*)d_in[22];
  const float* vh_b1 = (const float*)d_in[23];
  const float* vh_w2 = (const float*)d_in[24];
  const float* vh_b2 = (const float*)d_in[25];
  const float* om_w = (const float*)d_in[26];
  const float* om_b = (const float*)d_in[27];
  const float* op_w1 = (const float*)d_in[28];
  const float* op_b1 = (const float*)d_in[29];
  const float* op_w2 = (const float*)d_in[30];
  const float* op_b2 = (const float*)d_in[31];
  float* ws = (float*)d_ws;
  float* out = (float*)d_out;

  (void)hipFuncSetAttribute((const void*)k_attn,
                            hipFuncAttributeMaxDynamicSharedMemorySize,
                            ATTN_LDS_BYTES);

  k_init<<<64, 256, 0, stream>>>(board, ws);
  k_stem<<<256, 256, 0, stream>>>(board, stem_w, ws);
  k_gn_silu<<<2048, 256, 0, stream>>>(ws + WSX, stem_g, stem_b, ws + WSS);

  for (int i = 0; i < 6; ++i) {
    float* s1 = ws + WSS + (size_t)(1 + 2 * i) * 2048;
    float* s2 = ws + WSS + (size_t)(2 + 2 * i) * 2048;
    if (i == 0) {
      k_attn<<<512, 512, ATTN_LDS_BYTES, stream>>>(
          ws + WSX, ws + WSX, ws + WSS, gn2_g, gn2_b, ws + WST,
          qw, qb, kw, kb, vw, vb, ow, ob, ln_g, ln_b, ws + WSP, 0);
    } else {
      float* s2prev = ws + WSS + (size_t)(2 * i) * 2048;
      k_attn<<<512, 512, ATTN_LDS_BYTES, stream>>>(
          ws + WST, ws + WSY, s2prev, gn2_g + (i - 1) * 64, gn2_b + (i - 1) * 64,
          ws + WST, qw + i * 4096, qb + i * 64, kw + i * 4096, kb + i * 64,
          vw + i * 4096, vb + i * 64, ow + i * 4096, ob + i * 64, ln_g + i * 64,
          ln_b + i * 64, ws + WSP, 1);
    }
    k_dw<<<512, 256, 0, stream>>>(ws + WST, ws + WSY, dw_w + i * 576, s1, ws + WSP);
    k_pw<<<512, 256, 0, stream>>>(ws + WSY, pw_w + i * 4096, gn1_g + i * 64,
                                  gn1_b + i * 64, s1, s2, ws + WSP);
  }
  // final layer epilogue -> X for heads
  k_fuse<<<1024, 256, 0, stream>>>(ws + WST, ws + WSY, ws + WSX, gn2_g + 5 * 64,
                                   gn2_b + 5 * 64, ws + WSS + (size_t)12 * 2048,
                                   ws + WSP);

  k_heads_px<<<256, 256, 0, stream>>>(ws + WSX, pol_w, pol_b, om_w, om_b, ws + WSP, out);
  k_pool<<<128, 256, 0, stream>>>(ws + WSX, ws + WSPL);
  k_heads_vec<<<128, 64, 0, stream>>>(ws + WSPL, vh_w1, vh_b1, vh_w2, vh_b2, op_w1,
                                      op_b1, op_w2, op_b2, ws + WSP, out);
}